// Round 5
// baseline (440.377 us; speedup 1.0000x reference)
//
#include <hip/hip_runtime.h>

typedef unsigned short u16;
typedef __bf16 bf16x8 __attribute__((ext_vector_type(8)));
typedef float f32x4 __attribute__((ext_vector_type(4)));

#define DEV static __device__ __forceinline__

constexpr int Bc  = 2;
constexpr int Lc  = 2048;
constexpr int Dc  = 2048;
constexpr int Hc  = 16;
constexpr int HDc = 128;
constexpr int Mc  = Bc * Lc;   // 4096
constexpr int N3c = 3 * Dc;    // 6144

DEV u16 f2bf(float f) {
  unsigned u = __builtin_bit_cast(unsigned, f);
  u += 0x7fffu + ((u >> 16) & 1u);
  return (u16)(u >> 16);
}
DEV float bf2f(u16 h) { return __builtin_bit_cast(float, ((unsigned)h) << 16); }

DEV void load16(const void* g, void* l) {
  __builtin_amdgcn_global_load_lds(
      (__attribute__((address_space(1))) void*)(g),
      (__attribute__((address_space(3))) void*)(l), 16, 0, 0);
}

// ---------------- merged prep: x->bf16 convert + both weight transposes ----------------
__global__ __launch_bounds__(256) void k_prep(const float* __restrict__ x,
                                              const float* __restrict__ w_qkv,
                                              const float* __restrict__ w_proj,
                                              u16* __restrict__ xb,
                                              u16* __restrict__ wqkvT,
                                              u16* __restrict__ wpT) {
  __shared__ u16 t[128 * 136];
  int bid = blockIdx.x;
  int tid = threadIdx.x;
  if (bid < 4096) {
    int i = bid * 256 + tid;
    const float4* s = (const float4*)x;
    float4 a = s[2 * i], b = s[2 * i + 1];
    uint4 o;
    o.x = f2bf(a.x) | ((unsigned)f2bf(a.y) << 16);
    o.y = f2bf(a.z) | ((unsigned)f2bf(a.w) << 16);
    o.z = f2bf(b.x) | ((unsigned)f2bf(b.y) << 16);
    o.w = f2bf(b.z) | ((unsigned)f2bf(b.w) << 16);
    ((uint4*)xb)[i] = o;
    return;
  }
  const float* src;
  u16* dst;
  int tiles_c;
  long ss;
  if (bid < 4096 + 768) {
    int bx = bid - 4096;
    src = w_qkv; dst = wqkvT; tiles_c = 48; ss = N3c;
    int tr = bx / tiles_c, tc = bx % tiles_c;
    src += (long)tr * 128 * ss + tc * 128;
    dst += (long)(tc * 128) * Dc + tr * 128;
  } else {
    int bx = bid - 4864;
    src = w_proj; dst = wpT; tiles_c = 16; ss = Dc;
    int tr = bx / tiles_c, tc = bx % tiles_c;
    src += (long)tr * 128 * ss + tc * 128;
    dst += (long)(tc * 128) * Dc + tr * 128;
  }
#pragma unroll
  for (int p = 0; p < 16; p++) {
    int r = p * 8 + (tid >> 5);
    int c4 = (tid & 31) * 4;
    float4 v = *(const float4*)(src + (long)r * ss + c4);
    t[(c4 + 0) * 136 + r] = f2bf(v.x);
    t[(c4 + 1) * 136 + r] = f2bf(v.y);
    t[(c4 + 2) * 136 + r] = f2bf(v.z);
    t[(c4 + 3) * 136 + r] = f2bf(v.w);
  }
  __syncthreads();
#pragma unroll
  for (int p = 0; p < 8; p++) {
    int c = p * 16 + (tid >> 4);
    int r8 = (tid & 15) * 8;
    uint4 v = *(const uint4*)&t[c * 136 + r8];
    *(uint4*)(dst + (long)c * Dc + r8) = v;
  }
}

// ------- bf16 V transpose: Vt[bh][d][l] = qkvb[b*L+l][4096 + h*128 + d] -------
__global__ __launch_bounds__(256) void k_vtrans(const u16* __restrict__ qkvb,
                                                u16* __restrict__ Vt) {
  int lt = blockIdx.x;   // 0..15 (tile over L)
  int bh = blockIdx.y;   // 0..31
  int b = bh >> 4, h = bh & 15;
  const u16* s = qkvb + (long)(b * Lc + lt * 128) * N3c + 2 * Dc + h * HDc;
  u16* d = Vt + (long)bh * HDc * Lc + lt * 128;
  __shared__ u16 t[128 * 136];
  int tid = threadIdx.x;
#pragma unroll
  for (int p = 0; p < 8; p++) {
    int r = p * 16 + (tid >> 4);
    int c = (tid & 15) * 8;
    uint4 v = *(const uint4*)(s + (long)r * N3c + c);
    const u16* pv = (const u16*)&v;
#pragma unroll
    for (int j = 0; j < 8; j++) t[(c + j) * 136 + r] = pv[j];
  }
  __syncthreads();
#pragma unroll
  for (int p = 0; p < 8; p++) {
    int c = p * 16 + (tid >> 4);
    int r8 = (tid & 15) * 8;
    *(uint4*)(d + (long)c * Lc + r8) = *(const uint4*)&t[c * 136 + r8];
  }
}

DEV void cstore(float* p, float v) { *p = v; }
DEV void cstore(u16* p, float v) { *p = f2bf(v); }

// ---- 128x256-tile bf16 MFMA GEMM: reg-double-buffered frags, 1 barrier/K-tile ----
// C[M][N] = A[M][K] * Bt[N][K]^T.  BM=128, BN=256, BK=64, 8 waves (2M x 4N),
// per-wave 64x64.  LDS 3 bufs x 48KB = 144KB (1 blk/CU, 8 waves).
// 2D XCD regions (RM brows x RC bcols per XCD) for L2 locality.
// Software pipeline per K-tile t (read buf ri=(t+1)%3, stage buf si=t%3):
//   vmcnt(6)  -> own t+1 stage loads landed (keep t+2 flying)
//   SB BAR SB -> all waves' t+1 landed; all waves' reads of buf si drained (t-1 lgkm0)
//   STAGE(t+3 -> buf si)                       (overwrites data last read at t-1)
//   ds_read frags(t+1) from buf ri -> regNEXT  (no lgkm drain -- compiler interleaves)
//   MFMA x32 on regCUR                         (operands loaded last tile)
//   lgkmcnt(0)                                 (reads drained before next BAR)
// Per-wave queue: 6 loads/tile; entering t in-flight = {t+1,t+2} = 12.
template <typename OT>
__global__ __launch_bounds__(512, 2) void k_gemm2p(const u16* __restrict__ A,
                                                   const u16* __restrict__ Bt,
                                                   OT* __restrict__ C,
                                                   int M, int N, int K,
                                                   int RM, int RC) {
  __shared__ __align__(16) u16 sA[3][128 * 64];
  __shared__ __align__(16) u16 sB[3][256 * 64];

  int nb = N >> 8;
  int x = blockIdx.x & 7;        // XCD id (grid % 8 == 0)
  int u = blockIdx.x >> 3;       // local block within XCD region
  int rcr = nb / RC;             // # of region-columns
  int brow = (x / rcr) * RM + (u % RM);
  int bcol = (x % rcr) * RC + (u / RM);

  int tid = threadIdx.x, w = tid >> 6, lane = tid & 63;
  int wm = w >> 2, wn = w & 3;
  int quad = lane >> 4, l15 = lane & 15;
  int lr = lane >> 3, lc = lane & 7;
  int NT = K >> 6;

  const u16* Ag = A + (long)(brow * 128 + w * 8 + lr) * K + (lc ^ lr) * 8;
  const u16* Bg = Bt + (long)(bcol * 256 + w * 8 + lr) * K + (lc ^ lr) * 8;

  f32x4 acc[4][4] = {};
  bf16x8 a0[4][2], b0[4][2];  // reg set 0
  bf16x8 a1[4][2], b1[4][2];  // reg set 1

#define STAGE(c, t)                                                            \
  if ((t) < NT) {                                                              \
    _Pragma("unroll") for (int j = 0; j < 2; j++)                              \
        load16(Ag + (long)(j * 64) * K + (long)(t) * 64,                       \
               &sA[c][(j * 64 + w * 8) * 64]);                                 \
    _Pragma("unroll") for (int j = 0; j < 4; j++)                              \
        load16(Bg + (long)(j * 64) * K + (long)(t) * 64,                       \
               &sB[c][(j * 64 + w * 8) * 64]);                                 \
  }
#define LDAB(c, ar, br)                                                        \
  _Pragma("unroll") for (int mi = 0; mi < 4; mi++) {                           \
    int r = wm * 64 + mi * 16 + l15;                                           \
    _Pragma("unroll") for (int kk = 0; kk < 2; kk++)                           \
        ar[mi][kk] =                                                           \
        *(const bf16x8*)&sA[c][r * 64 + (((kk * 4 + quad) ^ (r & 7)) << 3)];   \
  }                                                                            \
  _Pragma("unroll") for (int fi = 0; fi < 4; fi++) {                           \
    int rn = wn * 64 + fi * 16 + l15;                                          \
    _Pragma("unroll") for (int kk = 0; kk < 2; kk++)                           \
        br[fi][kk] =                                                           \
        *(const bf16x8*)&sB[c][rn * 64 + (((kk * 4 + quad) ^ (rn & 7)) << 3)]; \
  }
#define MFMAALL(ar, br)                                                        \
  _Pragma("unroll") for (int mi = 0; mi < 4; mi++)                             \
  _Pragma("unroll") for (int fi = 0; fi < 4; fi++)                             \
  _Pragma("unroll") for (int kk = 0; kk < 2; kk++)                             \
      acc[mi][fi] = __builtin_amdgcn_mfma_f32_16x16x32_bf16(                   \
          ar[mi][kk], br[fi][kk], acc[mi][fi], 0, 0, 0);
#define SB() __builtin_amdgcn_sched_barrier(0)
#define BAR() __builtin_amdgcn_s_barrier()
#define WAITV(n) asm volatile("s_waitcnt vmcnt(" #n ")" ::: "memory")
#define WAITL0() asm volatile("s_waitcnt lgkmcnt(0)" ::: "memory")

#define TILE_BODY(tt, sbuf, rbuf, arC, brC, arN, brN, vkeep)                   \
  {                                                                            \
    WAITV(vkeep);                                                              \
    SB();                                                                      \
    BAR();                                                                     \
    SB();                                                                      \
    STAGE(sbuf, (tt) + 3);                                                     \
    LDAB(rbuf, arN, brN);                                                      \
    __builtin_amdgcn_s_setprio(1);                                             \
    MFMAALL(arC, brC);                                                         \
    __builtin_amdgcn_s_setprio(0);                                             \
    WAITL0();                                                                  \
  }

  // prologue: stage tiles 0,1,2 into bufs 0,1,2; drain tile 0; preload frags(0)
  STAGE(0, 0);
  STAGE(1, 1);
  STAGE(2, 2);
  WAITV(12);
  SB();
  BAR();
  SB();
  LDAB(0, a0, b0);
  WAITL0();  // frags(0) drained before tile0's BAR (buf0 is tile0's stage target)

  int si = 0, ri = 1;
  int t = 0;
  for (; t < NT - 2; t += 2) {
    TILE_BODY(t, si, ri, a0, b0, a1, b1, 6);
    si = si == 2 ? 0 : si + 1;
    ri = ri == 2 ? 0 : ri + 1;
    TILE_BODY(t + 1, si, ri, a1, b1, a0, b0, 6);
    si = si == 2 ? 0 : si + 1;
    ri = ri == 2 ? 0 : ri + 1;
  }
  // tile NT-2: compute set0, load frags(NT-1); no stage; drain all loads
  {
    WAITV(0);
    SB();
    BAR();
    SB();
    LDAB(ri, a1, b1);
    __builtin_amdgcn_s_setprio(1);
    MFMAALL(a0, b0);
    __builtin_amdgcn_s_setprio(0);
    WAITL0();
  }
  // tile NT-1: compute set1
  __builtin_amdgcn_s_setprio(1);
  MFMAALL(a1, b1);
  __builtin_amdgcn_s_setprio(0);

  long orow = (long)brow * 128 + wm * 64;
  int ocol = bcol * 256 + wn * 64;
#pragma unroll
  for (int mi = 0; mi < 4; mi++)
#pragma unroll
    for (int fi = 0; fi < 4; fi++)
#pragma unroll
      for (int r = 0; r < 4; r++)
        cstore(&C[(orow + mi * 16 + quad * 4 + r) * (long)N + ocol + fi * 16 + l15],
               acc[mi][fi][r]);
#undef STAGE
#undef LDAB
#undef MFMAALL
#undef SB
#undef BAR
#undef WAITV
#undef WAITL0
#undef TILE_BODY
}

// ---------------- fused RMS-norm + RoPE (Q pre-scaled by 1/sqrt(HD)) ----------------
__global__ __launch_bounds__(256) void k_rmsrope(const u16* __restrict__ qkvb,
                                                 const float* __restrict__ pe,
                                                 const float* __restrict__ qsc,
                                                 const float* __restrict__ ksc,
                                                 u16* __restrict__ Qr,
                                                 u16* __restrict__ Kr) {
  int row = blockIdx.x;  // b*L + l
  int l = row & (Lc - 1);
  int b = row >> 11;
  int tid = threadIdx.x;
  int h = tid >> 4, s16 = tid & 15;
  int d0 = s16 * 8;
  const u16* qp = qkvb + (long)row * N3c + h * HDc + d0;
  uint4 qv = *(const uint4*)qp;
  uint4 kv = *(const uint4*)(qp + Dc);
  const u16* qu = (const u16*)&qv;
  const u16* ku = (const u16*)&kv;
  float q[8], k[8];
#pragma unroll
  for (int j = 0; j < 8; j++) {
    q[j] = bf2f(qu[j]);
    k[j] = bf2f(ku[j]);
  }
  float sq = 0.f, sk = 0.f;
#pragma unroll
  for (int j = 0; j < 8; j++) {
    sq += q[j] * q[j];
    sk += k[j] * k[j];
  }
#pragma unroll
  for (int m = 1; m < 16; m <<= 1) {
    sq += __shfl_xor(sq, m);
    sk += __shfl_xor(sk, m);
  }
  float rq = rsqrtf(sq * (1.f / HDc) + 1e-6f);
  float rk = rsqrtf(sk * (1.f / HDc) + 1e-6f);
  float qs8[8], ks8[8];
  *(float4*)&qs8[0] = *(const float4*)(qsc + d0);
  *(float4*)&qs8[4] = *(const float4*)(qsc + d0 + 4);
  *(float4*)&ks8[0] = *(const float4*)(ksc + d0);
  *(float4*)&ks8[4] = *(const float4*)(ksc + d0 + 4);
#pragma unroll
  for (int j = 0; j < 8; j++) {
    q[j] *= rq * qs8[j];
    k[j] *= rk * ks8[j];
  }
  float e[16];
  const float* pep = pe + (long)l * 256 + s16 * 16;
#pragma unroll
  for (int j = 0; j < 4; j++) *(float4*)&e[j * 4] = *(const float4*)(pep + j * 4);
  float qo[8], ko[8];
#pragma unroll
  for (int p = 0; p < 4; p++) {
    float e00 = e[p * 4 + 0], e01 = e[p * 4 + 1];
    float e10 = e[p * 4 + 2], e11 = e[p * 4 + 3];
    qo[2 * p]     = e00 * q[2 * p] + e01 * q[2 * p + 1];
    qo[2 * p + 1] = e10 * q[2 * p] + e11 * q[2 * p + 1];
    ko[2 * p]     = e00 * k[2 * p] + e01 * k[2 * p + 1];
    ko[2 * p + 1] = e10 * k[2 * p] + e11 * k[2 * p + 1];
  }
  constexpr float RS = 0.08838834764831845f;  // 1/sqrt(128)
  uint4 oq, ok;
  oq.x = f2bf(qo[0] * RS) | ((unsigned)f2bf(qo[1] * RS) << 16);
  oq.y = f2bf(qo[2] * RS) | ((unsigned)f2bf(qo[3] * RS) << 16);
  oq.z = f2bf(qo[4] * RS) | ((unsigned)f2bf(qo[5] * RS) << 16);
  oq.w = f2bf(qo[6] * RS) | ((unsigned)f2bf(qo[7] * RS) << 16);
  ok.x = f2bf(ko[0]) | ((unsigned)f2bf(ko[1]) << 16);
  ok.y = f2bf(ko[2]) | ((unsigned)f2bf(ko[3]) << 16);
  ok.z = f2bf(ko[4]) | ((unsigned)f2bf(ko[5]) << 16);
  ok.w = f2bf(ko[6]) | ((unsigned)f2bf(ko[7]) << 16);
  long o = (((long)(b * Hc + h)) * Lc + l) * HDc + d0;
  *(uint4*)(Qr + o) = oq;
  *(uint4*)(Kr + o) = ok;
}

// ---------------- flash attention v6: R2 structure + XCD swizzle ----------------
__global__ __launch_bounds__(256, 3) void k_attn(const u16* __restrict__ Qr,
                                                 const u16* __restrict__ Kr,
                                                 const u16* __restrict__ Vt,
                                                 u16* __restrict__ Ao) {
  __shared__ u16 smem[24576];  // 48 KB
  u16* sQ = smem;              // [64][128] staging; reused as sP [64][64] (8KB)
  u16* sK = smem + 8192;       // [64][128] 16KB; epilogue: red
  u16* sV = smem + 16384;      // [128][64] 16KB; epilogue: rsum
  u16* sP = sQ;
  int bx = blockIdx.x;
  int bh = (bx & 7) | ((bx >> 8) << 3);
  int lt = (bx >> 3) & 31;
  const u16* Qg = Qr + ((long)bh * Lc + lt * 64) * HDc;
  const u16* Kg = Kr + (long)bh * Lc * HDc;
  const u16* Vg = Vt + (long)bh * HDc * Lc;
  int tid = threadIdx.x, w = tid >> 6, lane = tid & 63;
  int quad = lane >> 4, l15 = lane & 15;
  int wsl = w >> 1, wsm = w & 1;  // S-phase wave grid: l x m
  int wd = w >> 1, wl2 = w & 1;   // PV-phase wave grid: d x l

#pragma unroll
  for (int i = 0; i < 4; i++) {
    int r = i * 16 + w * 4 + quad;
    int gch = l15 ^ (r & 15);
    load16(Qg + (long)r * HDc + gch * 8, sQ + (i * 16 + w * 4) * 128);
  }
  __syncthreads();
  bf16x8 qf[2][4];
#pragma unroll
  for (int mi = 0; mi < 2; mi++) {
    int l = wsl * 32 + mi * 16 + l15;
#pragma unroll
    for (int kk = 0; kk < 4; kk++)
      qf[mi][kk] = *(const bf16x8*)&sQ[l * 128 + (((kk * 4 + quad) ^ l15) << 3)];
  }

  f32x4 o[4][2] = {};
  float rs[8] = {};
  for (int t = 0; t < 32; t++) {
    int m0 = t * 64;
    __syncthreads();  // A: prev PV done reading sP/sV; Q frags read (t=0)
#pragma unroll
    for (int i = 0; i < 4; i++) {
      int r = i * 16 + w * 4 + quad;
      int gch = l15 ^ (r & 15);
      load16(Kg + ((long)(m0 + r)) * HDc + gch * 8, sK + (i * 16 + w * 4) * 128);
    }
#pragma unroll
    for (int i = 0; i < 4; i++) {
      int r = i * 32 + w * 8 + (lane >> 3);
      int gch = (lane & 7) ^ (r & 7);
      load16(Vg + (long)r * Lc + m0 + gch * 8, sV + (i * 32 + w * 8) * 64);
    }
    __syncthreads();  // B: staged
    f32x4 s[2][2] = {};
#pragma unroll
    for (int kk = 0; kk < 4; kk++) {
      bf16x8 bk[2];
#pragma unroll
      for (int ni = 0; ni < 2; ni++) {
        int m = wsm * 32 + ni * 16 + l15;
        bk[ni] = *(const bf16x8*)&sK[m * 128 + (((kk * 4 + quad) ^ l15) << 3)];
      }
#pragma unroll
      for (int mi = 0; mi < 2; mi++)
#pragma unroll
        for (int ni = 0; ni < 2; ni++)
          s[mi][ni] =
              __builtin_amdgcn_mfma_f32_16x16x32_bf16(qf[mi][kk], bk[ni], s[mi][ni], 0, 0, 0);
    }
#pragma unroll
    for (int mi = 0; mi < 2; mi++)
#pragma unroll
      for (int ni = 0; ni < 2; ni++) {
        int pc = wsm * 32 + ni * 16 + l15;
#pragma unroll
        for (int r = 0; r < 4; r++) {
          int pr = wsl * 32 + mi * 16 + quad * 4 + r;
          float p = __expf(s[mi][ni][r]);
          rs[mi * 4 + r] += p;
          unsigned u = __builtin_bit_cast(unsigned, p) + 0x8000u;
          sP[pr * 64 + ((((pc >> 3) ^ (pr & 7)) << 3) | (pc & 7))] = (u16)(u >> 16);
        }
      }
    __syncthreads();  // D: P visible
#pragma unroll
    for (int kk = 0; kk < 2; kk++) {
      bf16x8 av[4], bp[2];
#pragma unroll
      for (int mi = 0; mi < 4; mi++) {
        int d = wd * 64 + mi * 16 + l15;
        av[mi] = *(const bf16x8*)&sV[d * 64 + (((kk * 4 + quad) ^ (d & 7)) << 3)];
      }
#pragma unroll
      for (int ni = 0; ni < 2; ni++) {
        int l = wl2 * 32 + ni * 16 + l15;
        bp[ni] = *(const bf16x8*)&sP[l * 64 + (((kk * 4 + quad) ^ (l & 7)) << 3)];
      }
#pragma unroll
      for (int mi = 0; mi < 4; mi++)
#pragma unroll
        for (int ni = 0; ni < 2; ni++)
          o[mi][ni] =
              __builtin_amdgcn_mfma_f32_16x16x32_bf16(av[mi], bp[ni], o[mi][ni], 0, 0, 0);
    }
  }
  __syncthreads();
  float* red  = (float*)sK;  // [64][33]
  float* rsum = (float*)sV;  // [64]
#pragma unroll
  for (int mi = 0; mi < 2; mi++)
#pragma unroll
    for (int r = 0; r < 4; r++) {
      int l = wsl * 32 + mi * 16 + quad * 4 + r;
      red[l * 33 + wsm * 16 + l15] = rs[mi * 4 + r];
    }
  __syncthreads();
  if (tid < 64) {
    float a = 0.f;
#pragma unroll
    for (int j = 0; j < 32; j++) a += red[tid * 33 + j];
    rsum[tid] = a;
  }
  __syncthreads();
  int b = bh >> 4, h = bh & 15;
#pragma unroll
  for (int ni = 0; ni < 2; ni++) {
    int l = wl2 * 32 + ni * 16 + l15;
    float inv = 1.f / rsum[l];
    long rowb = ((long)(b * Lc + lt * 64 + l)) * Dc + h * HDc;
#pragma unroll
    for (int mi = 0; mi < 4; mi++) {
      int d = wd * 64 + mi * 16 + quad * 4;
      ushort4 pk;
      pk.x = f2bf(o[mi][ni][0] * inv);
      pk.y = f2bf(o[mi][ni][1] * inv);
      pk.z = f2bf(o[mi][ni][2] * inv);
      pk.w = f2bf(o[mi][ni][3] * inv);
      *(ushort4*)(Ao + rowb + d) = pk;
    }
  }
}

extern "C" void kernel_launch(void* const* d_in, const int* in_sizes, int n_in,
                              void* d_out, int out_size, void* d_ws, size_t ws_size,
                              hipStream_t stream) {
  const float* x      = (const float*)d_in[0];
  const float* pe     = (const float*)d_in[1];
  const float* w_qkv  = (const float*)d_in[2];
  const float* w_proj = (const float*)d_in[3];
  const float* qs     = (const float*)d_in[4];
  const float* ks     = (const float*)d_in[5];
  float* out = (float*)d_out;
  char* ws = (char*)d_ws;

  u16* xb    = (u16*)(ws);                  //  16.8 MB  x bf16 [4096][2048]
  u16* wqkvT = (u16*)(ws + 16777216);       //  25.2 MB  [6144][2048]
  u16* wpT   = (u16*)(ws + 41943040);       //   8.4 MB  [2048][2048]
  u16* qkvb  = (u16*)(ws + 50331648);       //  50.3 MB  [4096][6144] bf16
  u16* Qr    = (u16*)(ws + 100663296);      //  16.8 MB  [B][H][L][HD]
  u16* Kr    = (u16*)(ws + 117440512);      //  16.8 MB
  u16* Vtw   = (u16*)(ws + 134217728);      //  16.8 MB  [B][H][HD][L]
  u16* Ao    = (u16*)(ws + 150994944);      //  16.8 MB  [4096][2048] bf16

  k_prep<<<5120, 256, 0, stream>>>(x, w_qkv, w_proj, xb, wqkvT, wpT);
  // QKV: grid 768 = 8 XCD regions of 16 brows x 6 bcols
  k_gemm2p<u16><<<32 * 24, 512, 0, stream>>>(xb, wqkvT, qkvb, Mc, N3c, Dc, 16, 6);
  k_rmsrope<<<Mc, 256, 0, stream>>>(qkvb, pe, qs, ks, Qr, Kr);
  k_vtrans<<<dim3(16, 32), 256, 0, stream>>>(qkvb, Vtw);
  k_attn<<<32 * 32, 256, 0, stream>>>(Qr, Kr, Vtw, Ao);
  // proj: grid 256 = 8 XCD regions of 8 brows x 4 bcols
  k_gemm2p<float><<<32 * 8, 512, 0, stream>>>(Ao, wpT, out, Mc, Dc, Dc, 8, 4);
}

// Round 6
// 408.353 us; speedup vs baseline: 1.0784x; 1.0784x over previous
//
#include <hip/hip_runtime.h>

typedef unsigned short u16;
typedef __bf16 bf16x8 __attribute__((ext_vector_type(8)));
typedef float f32x4 __attribute__((ext_vector_type(4)));

#define DEV static __device__ __forceinline__

constexpr int Bc  = 2;
constexpr int Lc  = 2048;
constexpr int Dc  = 2048;
constexpr int Hc  = 16;
constexpr int HDc = 128;
constexpr int Mc  = Bc * Lc;   // 4096
constexpr int N3c = 3 * Dc;    // 6144

DEV u16 f2bf(float f) {
  unsigned u = __builtin_bit_cast(unsigned, f);
  u += 0x7fffu + ((u >> 16) & 1u);
  return (u16)(u >> 16);
}
DEV float bf2f(u16 h) { return __builtin_bit_cast(float, ((unsigned)h) << 16); }

DEV void load16(const void* g, void* l) {
  __builtin_amdgcn_global_load_lds(
      (__attribute__((address_space(1))) void*)(g),
      (__attribute__((address_space(3))) void*)(l), 16, 0, 0);
}

// ---------------- merged prep: x->bf16 convert + both weight transposes ----------------
__global__ __launch_bounds__(256) void k_prep(const float* __restrict__ x,
                                              const float* __restrict__ w_qkv,
                                              const float* __restrict__ w_proj,
                                              u16* __restrict__ xb,
                                              u16* __restrict__ wqkvT,
                                              u16* __restrict__ wpT) {
  __shared__ u16 t[128 * 136];
  int bid = blockIdx.x;
  int tid = threadIdx.x;
  if (bid < 4096) {
    int i = bid * 256 + tid;
    const float4* s = (const float4*)x;
    float4 a = s[2 * i], b = s[2 * i + 1];
    uint4 o;
    o.x = f2bf(a.x) | ((unsigned)f2bf(a.y) << 16);
    o.y = f2bf(a.z) | ((unsigned)f2bf(a.w) << 16);
    o.z = f2bf(b.x) | ((unsigned)f2bf(b.y) << 16);
    o.w = f2bf(b.z) | ((unsigned)f2bf(b.w) << 16);
    ((uint4*)xb)[i] = o;
    return;
  }
  const float* src;
  u16* dst;
  int tiles_c;
  long ss;
  if (bid < 4096 + 768) {
    int bx = bid - 4096;
    src = w_qkv; dst = wqkvT; tiles_c = 48; ss = N3c;
    int tr = bx / tiles_c, tc = bx % tiles_c;
    src += (long)tr * 128 * ss + tc * 128;
    dst += (long)(tc * 128) * Dc + tr * 128;
  } else {
    int bx = bid - 4864;
    src = w_proj; dst = wpT; tiles_c = 16; ss = Dc;
    int tr = bx / tiles_c, tc = bx % tiles_c;
    src += (long)tr * 128 * ss + tc * 128;
    dst += (long)(tc * 128) * Dc + tr * 128;
  }
#pragma unroll
  for (int p = 0; p < 16; p++) {
    int r = p * 8 + (tid >> 5);
    int c4 = (tid & 31) * 4;
    float4 v = *(const float4*)(src + (long)r * ss + c4);
    t[(c4 + 0) * 136 + r] = f2bf(v.x);
    t[(c4 + 1) * 136 + r] = f2bf(v.y);
    t[(c4 + 2) * 136 + r] = f2bf(v.z);
    t[(c4 + 3) * 136 + r] = f2bf(v.w);
  }
  __syncthreads();
#pragma unroll
  for (int p = 0; p < 8; p++) {
    int c = p * 16 + (tid >> 4);
    int r8 = (tid & 15) * 8;
    uint4 v = *(const uint4*)&t[c * 136 + r8];
    *(uint4*)(dst + (long)c * Dc + r8) = v;
  }
}

// ------- bf16 V transpose: Vt[bh][d][l] = qkvb[b*L+l][4096 + h*128 + d] -------
__global__ __launch_bounds__(256) void k_vtrans(const u16* __restrict__ qkvb,
                                                u16* __restrict__ Vt) {
  int lt = blockIdx.x;   // 0..15 (tile over L)
  int bh = blockIdx.y;   // 0..31
  int b = bh >> 4, h = bh & 15;
  const u16* s = qkvb + (long)(b * Lc + lt * 128) * N3c + 2 * Dc + h * HDc;
  u16* d = Vt + (long)bh * HDc * Lc + lt * 128;
  __shared__ u16 t[128 * 136];
  int tid = threadIdx.x;
#pragma unroll
  for (int p = 0; p < 8; p++) {
    int r = p * 16 + (tid >> 4);
    int c = (tid & 15) * 8;
    uint4 v = *(const uint4*)(s + (long)r * N3c + c);
    const u16* pv = (const u16*)&v;
#pragma unroll
    for (int j = 0; j < 8; j++) t[(c + j) * 136 + r] = pv[j];
  }
  __syncthreads();
#pragma unroll
  for (int p = 0; p < 8; p++) {
    int c = p * 16 + (tid >> 4);
    int r8 = (tid & 15) * 8;
    *(uint4*)(d + (long)c * Lc + r8) = *(const uint4*)&t[c * 136 + r8];
  }
}

DEV void cstore(float* p, float v) { *p = v; }
DEV void cstore(u16* p, float v) { *p = f2bf(v); }

// ------- 2-phase 128x256-tile bf16 MFMA GEMM, 3-deep pipeline + 2D XCD regions -------
// (best measured variant, R4: QKV 116 us / 889 TF)
template <typename OT>
__global__ __launch_bounds__(512, 2) void k_gemm2p(const u16* __restrict__ A,
                                                   const u16* __restrict__ Bt,
                                                   OT* __restrict__ C,
                                                   int M, int N, int K,
                                                   int RM, int RC) {
  __shared__ __align__(16) u16 sA[3][128 * 64];
  __shared__ __align__(16) u16 sB[3][256 * 64];

  int nb = N >> 8;
  int x = blockIdx.x & 7;        // XCD id (grid % 8 == 0)
  int u = blockIdx.x >> 3;       // local block within XCD region
  int rcr = nb / RC;             // # of region-columns
  int brow = (x / rcr) * RM + (u % RM);
  int bcol = (x % rcr) * RC + (u / RM);

  int tid = threadIdx.x, w = tid >> 6, lane = tid & 63;
  int wm = w >> 2, wn = w & 3;
  int quad = lane >> 4, l15 = lane & 15;
  int lr = lane >> 3, lc = lane & 7;
  int NT = K >> 6;

  const u16* Ag = A + (long)(brow * 128 + w * 8 + lr) * K + (lc ^ lr) * 8;
  const u16* Bg = Bt + (long)(bcol * 256 + w * 8 + lr) * K + (lc ^ lr) * 8;

  f32x4 acc[4][4] = {};
  bf16x8 a[4][2];  // all 4 m-frags: [mi][kk]
  bf16x8 b[4][2];  // all 4 n-frags: [fi][kk]

#define STAGE_A(c, t)                                                          \
  if ((t) < NT) {                                                              \
    _Pragma("unroll") for (int j = 0; j < 2; j++)                              \
        load16(Ag + (long)(j * 64) * K + (long)(t) * 64,                       \
               &sA[c][(j * 64 + w * 8) * 64]);                                 \
  }
#define STAGE_B(c, t)                                                          \
  if ((t) < NT) {                                                              \
    _Pragma("unroll") for (int j = 0; j < 4; j++)                              \
        load16(Bg + (long)(j * 64) * K + (long)(t) * 64,                       \
               &sB[c][(j * 64 + w * 8) * 64]);                                 \
  }
#define LDAB(c)                                                                \
  _Pragma("unroll") for (int mi = 0; mi < 4; mi++) {                           \
    int r = wm * 64 + mi * 16 + l15;                                           \
    _Pragma("unroll") for (int kk = 0; kk < 2; kk++)                           \
        a[mi][kk] =                                                            \
        *(const bf16x8*)&sA[c][r * 64 + (((kk * 4 + quad) ^ (r & 7)) << 3)];   \
  }                                                                            \
  _Pragma("unroll") for (int fi = 0; fi < 4; fi++) {                           \
    int rn = wn * 64 + fi * 16 + l15;                                          \
    _Pragma("unroll") for (int kk = 0; kk < 2; kk++)                           \
        b[fi][kk] =                                                            \
        *(const bf16x8*)&sB[c][rn * 64 + (((kk * 4 + quad) ^ (rn & 7)) << 3)]; \
  }
#define MFMAH(qm)                                                              \
  _Pragma("unroll") for (int mi = 0; mi < 2; mi++)                             \
  _Pragma("unroll") for (int fi = 0; fi < 4; fi++)                             \
  _Pragma("unroll") for (int kk = 0; kk < 2; kk++)                             \
      acc[(qm)*2 + mi][fi] = __builtin_amdgcn_mfma_f32_16x16x32_bf16(          \
          a[(qm)*2 + mi][kk], b[fi][kk], acc[(qm)*2 + mi][fi], 0, 0, 0);
#define BAR() __builtin_amdgcn_s_barrier()
#define LGKM0()                                      \
  asm volatile("s_waitcnt lgkmcnt(0)" ::: "memory"); \
  __builtin_amdgcn_sched_barrier(0)

#define TILE(c, t)                                                             \
  {                                                                            \
    LDAB(c);                                                                   \
    LGKM0();                                                                   \
    __builtin_amdgcn_s_setprio(1);                                             \
    MFMAH(0);                                                                  \
    __builtin_amdgcn_s_setprio(0);                                             \
    BAR(); /* mid: all waves' reads of buf c complete */                       \
    STAGE_A(c, (t) + 3);                                                       \
    STAGE_B(c, (t) + 3);                                                       \
    __builtin_amdgcn_s_setprio(1);                                             \
    MFMAH(1);                                                                  \
    __builtin_amdgcn_s_setprio(0);                                             \
    if ((t) < NT - 3) {                                                        \
      asm volatile("s_waitcnt vmcnt(12)" ::: "memory");                        \
    } else if ((t) == NT - 3) {                                                \
      asm volatile("s_waitcnt vmcnt(6)" ::: "memory");                         \
    } else {                                                                   \
      asm volatile("s_waitcnt vmcnt(0)" ::: "memory");                         \
    }                                                                          \
    __builtin_amdgcn_sched_barrier(0);                                         \
    BAR(); /* end: t+1's staged data visible to all */                         \
  }

  // prologue: stage tiles 0,1,2 into bufs 0,1,2; drain tile 0, keep 1,2 flying
  STAGE_A(0, 0);
  STAGE_B(0, 0);
  STAGE_A(1, 1);
  STAGE_B(1, 1);
  STAGE_A(2, 2);
  STAGE_B(2, 2);
  asm volatile("s_waitcnt vmcnt(12)" ::: "memory");
  __builtin_amdgcn_sched_barrier(0);
  BAR();

  int kt = 0;
  for (; kt + 2 < NT; kt += 3) {
    TILE(0, kt);
    TILE(1, kt + 1);
    TILE(2, kt + 2);
  }
  // NT = 32: epilogue tiles 30 (buf 0), 31 (buf 1)
  if (kt < NT) { TILE(0, kt); }
  if (kt + 1 < NT) { TILE(1, kt + 1); }

  long orow = (long)brow * 128 + wm * 64;
  int ocol = bcol * 256 + wn * 64;
#pragma unroll
  for (int mi = 0; mi < 4; mi++)
#pragma unroll
    for (int fi = 0; fi < 4; fi++)
#pragma unroll
      for (int r = 0; r < 4; r++)
        cstore(&C[(orow + mi * 16 + quad * 4 + r) * (long)N + ocol + fi * 16 + l15],
               acc[mi][fi][r]);
#undef STAGE_A
#undef STAGE_B
#undef LDAB
#undef MFMAH
#undef BAR
#undef LGKM0
#undef TILE
}

// ---------------- fused RMS-norm + RoPE (Q pre-scaled by 1/sqrt(HD)) ----------------
__global__ __launch_bounds__(256) void k_rmsrope(const u16* __restrict__ qkvb,
                                                 const float* __restrict__ pe,
                                                 const float* __restrict__ qsc,
                                                 const float* __restrict__ ksc,
                                                 u16* __restrict__ Qr,
                                                 u16* __restrict__ Kr) {
  int row = blockIdx.x;  // b*L + l
  int l = row & (Lc - 1);
  int b = row >> 11;
  int tid = threadIdx.x;
  int h = tid >> 4, s16 = tid & 15;
  int d0 = s16 * 8;
  const u16* qp = qkvb + (long)row * N3c + h * HDc + d0;
  uint4 qv = *(const uint4*)qp;
  uint4 kv = *(const uint4*)(qp + Dc);
  const u16* qu = (const u16*)&qv;
  const u16* ku = (const u16*)&kv;
  float q[8], k[8];
#pragma unroll
  for (int j = 0; j < 8; j++) {
    q[j] = bf2f(qu[j]);
    k[j] = bf2f(ku[j]);
  }
  float sq = 0.f, sk = 0.f;
#pragma unroll
  for (int j = 0; j < 8; j++) {
    sq += q[j] * q[j];
    sk += k[j] * k[j];
  }
#pragma unroll
  for (int m = 1; m < 16; m <<= 1) {
    sq += __shfl_xor(sq, m);
    sk += __shfl_xor(sk, m);
  }
  float rq = rsqrtf(sq * (1.f / HDc) + 1e-6f);
  float rk = rsqrtf(sk * (1.f / HDc) + 1e-6f);
  float qs8[8], ks8[8];
  *(float4*)&qs8[0] = *(const float4*)(qsc + d0);
  *(float4*)&qs8[4] = *(const float4*)(qsc + d0 + 4);
  *(float4*)&ks8[0] = *(const float4*)(ksc + d0);
  *(float4*)&ks8[4] = *(const float4*)(ksc + d0 + 4);
#pragma unroll
  for (int j = 0; j < 8; j++) {
    q[j] *= rq * qs8[j];
    k[j] *= rk * ks8[j];
  }
  float e[16];
  const float* pep = pe + (long)l * 256 + s16 * 16;
#pragma unroll
  for (int j = 0; j < 4; j++) *(float4*)&e[j * 4] = *(const float4*)(pep + j * 4);
  float qo[8], ko[8];
#pragma unroll
  for (int p = 0; p < 4; p++) {
    float e00 = e[p * 4 + 0], e01 = e[p * 4 + 1];
    float e10 = e[p * 4 + 2], e11 = e[p * 4 + 3];
    qo[2 * p]     = e00 * q[2 * p] + e01 * q[2 * p + 1];
    qo[2 * p + 1] = e10 * q[2 * p] + e11 * q[2 * p + 1];
    ko[2 * p]     = e00 * k[2 * p] + e01 * k[2 * p + 1];
    ko[2 * p + 1] = e10 * k[2 * p] + e11 * k[2 * p + 1];
  }
  constexpr float RS = 0.08838834764831845f;  // 1/sqrt(128)
  uint4 oq, ok;
  oq.x = f2bf(qo[0] * RS) | ((unsigned)f2bf(qo[1] * RS) << 16);
  oq.y = f2bf(qo[2] * RS) | ((unsigned)f2bf(qo[3] * RS) << 16);
  oq.z = f2bf(qo[4] * RS) | ((unsigned)f2bf(qo[5] * RS) << 16);
  oq.w = f2bf(qo[6] * RS) | ((unsigned)f2bf(qo[7] * RS) << 16);
  ok.x = f2bf(ko[0]) | ((unsigned)f2bf(ko[1]) << 16);
  ok.y = f2bf(ko[2]) | ((unsigned)f2bf(ko[3]) << 16);
  ok.z = f2bf(ko[4]) | ((unsigned)f2bf(ko[5]) << 16);
  ok.w = f2bf(ko[6]) | ((unsigned)f2bf(ko[7]) << 16);
  long o = (((long)(b * Hc + h)) * Lc + l) * HDc + d0;
  *(uint4*)(Qr + o) = oq;
  *(uint4*)(Kr + o) = ok;
}

// ------- flash attention v7: async staging (K post-D lds-dma, V reg-staged) -------
// Per tile t the staging for t+1 is ISSUED after BARRIER_D (under PV compute) and
// LANDS by the next BARRIER_A (syncthreads vmcnt drain):
//   A: PV(t-1) done reading sP/sV; K(t) in sK; V(t) in regs -> ds_write sV
//   B: sV visible (lgkm-only drain; no VM ops outstanding here)
//   S = QK^T ; exp -> sP
//   D: sP visible; ALL waves' S-reads of sK complete -> safe to overwrite sK
//   issue K(t+1) lds-dma + V(t+1) reg-loads; PV MFMAs (cover the latency)
// Reg WAR on vr[]: consumed (ds_write, latched at issue + lgkm drained by B)
// strictly before reload at D.
__global__ __launch_bounds__(256, 3) void k_attn(const u16* __restrict__ Qr,
                                                 const u16* __restrict__ Kr,
                                                 const u16* __restrict__ Vt,
                                                 u16* __restrict__ Ao) {
  __shared__ u16 smem[24576];  // 48 KB
  u16* sQ = smem;              // [64][128] staging; reused as sP [64][64] (8KB)
  u16* sK = smem + 8192;       // [64][128] 16KB; epilogue: red
  u16* sV = smem + 16384;      // [128][64] 16KB; epilogue: rsum
  u16* sP = sQ;
  int bx = blockIdx.x;
  int bh = (bx & 7) | ((bx >> 8) << 3);
  int lt = (bx >> 3) & 31;
  const u16* Qg = Qr + ((long)bh * Lc + lt * 64) * HDc;
  const u16* Kg = Kr + (long)bh * Lc * HDc;
  const u16* Vg = Vt + (long)bh * HDc * Lc;
  int tid = threadIdx.x, w = tid >> 6, lane = tid & 63;
  int quad = lane >> 4, l15 = lane & 15;
  int wsl = w >> 1, wsm = w & 1;  // S-phase wave grid: l x m
  int wd = w >> 1, wl2 = w & 1;   // PV-phase wave grid: d x l

  // V reg-stage addressing (same pre-swizzled pattern as the old lds-dma)
  int vrr0 = w * 8 + (lane >> 3);          // base row within 32-row group
  int vg0 = (lane & 7) ^ (vrr0 & 7);       // (r&7) invariant across i (i*32)
  const u16* Vg0 = Vg + (long)(vrr0 + 0)  * Lc + vg0 * 8;
  const u16* Vg1 = Vg + (long)(vrr0 + 32) * Lc + vg0 * 8;
  const u16* Vg2 = Vg + (long)(vrr0 + 64) * Lc + vg0 * 8;
  const u16* Vg3 = Vg + (long)(vrr0 + 96) * Lc + vg0 * 8;
  u16* sVw = sV + (w * 8) * 64 + lane * 8;  // per-lane ds_write dest (i adds 32*64)

  // ---- stage Q once (coalesced lds-dma), pull fragments into registers ----
#pragma unroll
  for (int i = 0; i < 4; i++) {
    int r = i * 16 + w * 4 + quad;
    int gch = l15 ^ (r & 15);
    load16(Qg + (long)r * HDc + gch * 8, sQ + (i * 16 + w * 4) * 128);
  }
  __syncthreads();
  bf16x8 qf[2][4];
#pragma unroll
  for (int mi = 0; mi < 2; mi++) {
    int l = wsl * 32 + mi * 16 + l15;
#pragma unroll
    for (int kk = 0; kk < 4; kk++)
      qf[mi][kk] = *(const bf16x8*)&sQ[l * 128 + (((kk * 4 + quad) ^ l15) << 3)];
  }

  // ---- prologue staging for tile 0: K via lds-dma, V into regs ----
#pragma unroll
  for (int i = 0; i < 4; i++) {
    int r = i * 16 + w * 4 + quad;
    int gch = l15 ^ (r & 15);
    load16(Kg + (long)r * HDc + gch * 8, sK + (i * 16 + w * 4) * 128);
  }
  uint4 vr0 = *(const uint4*)(Vg0);
  uint4 vr1 = *(const uint4*)(Vg1);
  uint4 vr2 = *(const uint4*)(Vg2);
  uint4 vr3 = *(const uint4*)(Vg3);

  f32x4 o[4][2] = {};
  float rs[8] = {};
  for (int t = 0; t < 32; t++) {
    int m0 = t * 64;
    __syncthreads();  // A: prev PV done; vmcnt drained -> sK(t) ready, vr = V(t)
    *(uint4*)(sVw + 0 * 32 * 64) = vr0;
    *(uint4*)(sVw + 1 * 32 * 64) = vr1;
    *(uint4*)(sVw + 2 * 32 * 64) = vr2;
    *(uint4*)(sVw + 3 * 32 * 64) = vr3;
    __syncthreads();  // B: sV visible (lgkm-only)
    // S = Q K^T  (64 l x 64 m; per wave 32x32 -> mi2 x ni2)
    f32x4 s[2][2] = {};
#pragma unroll
    for (int kk = 0; kk < 4; kk++) {
      bf16x8 bk[2];
#pragma unroll
      for (int ni = 0; ni < 2; ni++) {
        int m = wsm * 32 + ni * 16 + l15;
        bk[ni] = *(const bf16x8*)&sK[m * 128 + (((kk * 4 + quad) ^ l15) << 3)];
      }
#pragma unroll
      for (int mi = 0; mi < 2; mi++)
#pragma unroll
        for (int ni = 0; ni < 2; ni++)
          s[mi][ni] =
              __builtin_amdgcn_mfma_f32_16x16x32_bf16(qf[mi][kk], bk[ni], s[mi][ni], 0, 0, 0);
    }
    // exp + pack P into sP[l][m] (swizzled), accumulate row sums
#pragma unroll
    for (int mi = 0; mi < 2; mi++)
#pragma unroll
      for (int ni = 0; ni < 2; ni++) {
        int pc = wsm * 32 + ni * 16 + l15;
#pragma unroll
        for (int r = 0; r < 4; r++) {
          int pr = wsl * 32 + mi * 16 + quad * 4 + r;
          float p = __expf(s[mi][ni][r]);
          rs[mi * 4 + r] += p;
          unsigned u = __builtin_bit_cast(unsigned, p) + 0x8000u;
          sP[pr * 64 + ((((pc >> 3) ^ (pr & 7)) << 3) | (pc & 7))] = (u16)(u >> 16);
        }
      }
    __syncthreads();  // D: sP visible; all waves done reading sK
    // issue next tile's staging under PV compute
    if (t + 1 < 32) {
      int m1 = m0 + 64;
#pragma unroll
      for (int i = 0; i < 4; i++) {
        int r = i * 16 + w * 4 + quad;
        int gch = l15 ^ (r & 15);
        load16(Kg + ((long)(m1 + r)) * HDc + gch * 8, sK + (i * 16 + w * 4) * 128);
      }
      vr0 = *(const uint4*)(Vg0 + m1);
      vr1 = *(const uint4*)(Vg1 + m1);
      vr2 = *(const uint4*)(Vg2 + m1);
      vr3 = *(const uint4*)(Vg3 + m1);
    }
    // O^T += V^T P^T  (128 d x 64 l; per wave 64d x 32l -> mi4 x ni2)
#pragma unroll
    for (int kk = 0; kk < 2; kk++) {
      bf16x8 av[4], bp[2];
#pragma unroll
      for (int mi = 0; mi < 4; mi++) {
        int d = wd * 64 + mi * 16 + l15;
        av[mi] = *(const bf16x8*)&sV[d * 64 + (((kk * 4 + quad) ^ (d & 7)) << 3)];
      }
#pragma unroll
      for (int ni = 0; ni < 2; ni++) {
        int l = wl2 * 32 + ni * 16 + l15;
        bp[ni] = *(const bf16x8*)&sP[l * 64 + (((kk * 4 + quad) ^ (l & 7)) << 3)];
      }
#pragma unroll
      for (int mi = 0; mi < 4; mi++)
#pragma unroll
        for (int ni = 0; ni < 2; ni++)
          o[mi][ni] =
              __builtin_amdgcn_mfma_f32_16x16x32_bf16(av[mi], bp[ni], o[mi][ni], 0, 0, 0);
    }
  }
  // ---- epilogue: reduce row sums, scale, store O (b64 packed) ----
  __syncthreads();
  float* red  = (float*)sK;  // [64][33]
  float* rsum = (float*)sV;  // [64]
#pragma unroll
  for (int mi = 0; mi < 2; mi++)
#pragma unroll
    for (int r = 0; r < 4; r++) {
      int l = wsl * 32 + mi * 16 + quad * 4 + r;
      red[l * 33 + wsm * 16 + l15] = rs[mi * 4 + r];
    }
  __syncthreads();
  if (tid < 64) {
    float a = 0.f;
#pragma unroll
    for (int j = 0; j < 32; j++) a += red[tid * 33 + j];
    rsum[tid] = a;
  }
  __syncthreads();
  int b = bh >> 4, h = bh & 15;
#pragma unroll
  for (int ni = 0; ni < 2; ni++) {
    int l = wl2 * 32 + ni * 16 + l15;
    float inv = 1.f / rsum[l];
    long rowb = ((long)(b * Lc + lt * 64 + l)) * Dc + h * HDc;
#pragma unroll
    for (int mi = 0; mi < 4; mi++) {
      int d = wd * 64 + mi * 16 + quad * 4;
      ushort4 pk;
      pk.x = f2bf(o[mi][ni][0] * inv);
      pk.y = f2bf(o[mi][ni][1] * inv);
      pk.z = f2bf(o[mi][ni][2] * inv);
      pk.w = f2bf(o[mi][ni][3] * inv);
      *(ushort4*)(Ao + rowb + d) = pk;
    }
  }
}

extern "C" void kernel_launch(void* const* d_in, const int* in_sizes, int n_in,
                              void* d_out, int out_size, void* d_ws, size_t ws_size,
                              hipStream_t stream) {
  const float* x      = (const float*)d_in[0];
  const float* pe     = (const float*)d_in[1];
  const float* w_qkv  = (const float*)d_in[2];
  const float* w_proj = (const float*)d_in[3];
  const float* qs     = (const float*)d_in[4];
  const float* ks     = (const float*)d_in[5];
  float* out = (float*)d_out;
  char* ws = (char*)d_ws;

  u16* xb    = (u16*)(ws);                  //  16.8 MB  x bf16 [4096][2048]
  u16* wqkvT = (u16*)(ws + 16777216);       //  25.2 MB  [6144][2048]
  u16* wpT   = (u16*)(ws + 41943040);       //   8.4 MB  [2048][2048]
  u16* qkvb  = (u16*)(ws + 50331648);       //  50.3 MB  [4096][6144] bf16
  u16* Qr    = (u16*)(ws + 100663296);      //  16.8 MB  [B][H][L][HD]
  u16* Kr    = (u16*)(ws + 117440512);      //  16.8 MB
  u16* Vtw   = (u16*)(ws + 134217728);      //  16.8 MB  [B][H][HD][L]
  u16* Ao    = (u16*)(ws + 150994944);      //  16.8 MB  [4096][2048] bf16

  k_prep<<<5120, 256, 0, stream>>>(x, w_qkv, w_proj, xb, wqkvT, wpT);
  // QKV: grid 768 = 8 XCD regions of 16 brows x 6 bcols
  k_gemm2p<u16><<<32 * 24, 512, 0, stream>>>(xb, wqkvT, qkvb, Mc, N3c, Dc, 16, 6);
  k_rmsrope<<<Mc, 256, 0, stream>>>(qkvb, pe, qs, ks, Qr, Kr);
  k_vtrans<<<dim3(16, 32), 256, 0, stream>>>(qkvb, Vtw);
  k_attn<<<32 * 32, 256, 0, stream>>>(Qr, Kr, Vtw, Ao);
  // proj: grid 256 = 8 XCD regions of 8 brows x 4 bcols
  k_gemm2p<float><<<32 * 8, 512, 0, stream>>>(Ao, wpT, out, Mc, Dc, Dc, 8, 4);
}

// Round 7
// 395.462 us; speedup vs baseline: 1.1136x; 1.0326x over previous
//
#include <hip/hip_runtime.h>

typedef unsigned short u16;
typedef __bf16 bf16x8 __attribute__((ext_vector_type(8)));
typedef float f32x4 __attribute__((ext_vector_type(4)));

#define DEV static __device__ __forceinline__

constexpr int Bc  = 2;
constexpr int Lc  = 2048;
constexpr int Dc  = 2048;
constexpr int Hc  = 16;
constexpr int HDc = 128;
constexpr int Mc  = Bc * Lc;   // 4096
constexpr int N3c = 3 * Dc;    // 6144

DEV u16 f2bf(float f) {
  unsigned u = __builtin_bit_cast(unsigned, f);
  u += 0x7fffu + ((u >> 16) & 1u);
  return (u16)(u >> 16);
}
DEV float bf2f(u16 h) { return __builtin_bit_cast(float, ((unsigned)h) << 16); }

DEV void load16(const void* g, void* l) {
  __builtin_amdgcn_global_load_lds(
      (__attribute__((address_space(1))) void*)(g),
      (__attribute__((address_space(3))) void*)(l), 16, 0, 0);
}

// ---------------- merged prep: x->bf16 convert + both weight transposes ----------------
__global__ __launch_bounds__(256) void k_prep(const float* __restrict__ x,
                                              const float* __restrict__ w_qkv,
                                              const float* __restrict__ w_proj,
                                              u16* __restrict__ xb,
                                              u16* __restrict__ wqkvT,
                                              u16* __restrict__ wpT) {
  __shared__ u16 t[128 * 136];
  int bid = blockIdx.x;
  int tid = threadIdx.x;
  if (bid < 4096) {
    int i = bid * 256 + tid;
    const float4* s = (const float4*)x;
    float4 a = s[2 * i], b = s[2 * i + 1];
    uint4 o;
    o.x = f2bf(a.x) | ((unsigned)f2bf(a.y) << 16);
    o.y = f2bf(a.z) | ((unsigned)f2bf(a.w) << 16);
    o.z = f2bf(b.x) | ((unsigned)f2bf(b.y) << 16);
    o.w = f2bf(b.z) | ((unsigned)f2bf(b.w) << 16);
    ((uint4*)xb)[i] = o;
    return;
  }
  const float* src;
  u16* dst;
  int tiles_c;
  long ss;
  if (bid < 4096 + 768) {
    int bx = bid - 4096;
    src = w_qkv; dst = wqkvT; tiles_c = 48; ss = N3c;
    int tr = bx / tiles_c, tc = bx % tiles_c;
    src += (long)tr * 128 * ss + tc * 128;
    dst += (long)(tc * 128) * Dc + tr * 128;
  } else {
    int bx = bid - 4864;
    src = w_proj; dst = wpT; tiles_c = 16; ss = Dc;
    int tr = bx / tiles_c, tc = bx % tiles_c;
    src += (long)tr * 128 * ss + tc * 128;
    dst += (long)(tc * 128) * Dc + tr * 128;
  }
#pragma unroll
  for (int p = 0; p < 16; p++) {
    int r = p * 8 + (tid >> 5);
    int c4 = (tid & 31) * 4;
    float4 v = *(const float4*)(src + (long)r * ss + c4);
    t[(c4 + 0) * 136 + r] = f2bf(v.x);
    t[(c4 + 1) * 136 + r] = f2bf(v.y);
    t[(c4 + 2) * 136 + r] = f2bf(v.z);
    t[(c4 + 3) * 136 + r] = f2bf(v.w);
  }
  __syncthreads();
#pragma unroll
  for (int p = 0; p < 8; p++) {
    int c = p * 16 + (tid >> 4);
    int r8 = (tid & 15) * 8;
    uint4 v = *(const uint4*)&t[c * 136 + r8];
    *(uint4*)(dst + (long)c * Dc + r8) = v;
  }
}

DEV void cstore(float* p, float v) { *p = v; }
DEV void cstore(u16* p, float v) { *p = f2bf(v); }

// ------- 2-phase 128x256-tile bf16 MFMA GEMM, 3-deep pipeline + 2D XCD regions -------
// K-loop identical to R4 (best measured: 116-124 us QKV).  FUSE=true adds the
// QKV epilogue: per block = 128 rows x 2 heads.
//   Q/K blocks (bcol<16): RMS sumsq from fp32 accs (shfl over 16-lane group +
//     cross-wave partner wn^1 via 2KB LDS + 1 syncthreads), scale, RoPE (pair
//     partner via shfl_xor(v,1), per-lane float2 pe loads), Q x 1/sqrt(128);
//     per-wave 64x64 LDS transpose (stride-72 pad) -> coalesced stores to Qr/Kr.
//   V blocks (bcol>=16): per-wave LDS transpose [d][l] -> coalesced rows into
//     Vt[bh][d][l] directly (k_vtrans deleted; qkvb unused).
template <typename OT, bool FUSE>
__global__ __launch_bounds__(512, 2) void k_gemm2p(const u16* __restrict__ A,
                                                   const u16* __restrict__ Bt,
                                                   OT* __restrict__ C,
                                                   int M, int N, int K,
                                                   int RM, int RC,
                                                   const float* __restrict__ pe,
                                                   const float* __restrict__ qsc,
                                                   const float* __restrict__ ksc,
                                                   u16* __restrict__ Qr,
                                                   u16* __restrict__ Kr,
                                                   u16* __restrict__ Vt) {
  __shared__ __align__(16) u16 sA[3][128 * 64];
  __shared__ __align__(16) u16 sB[3][256 * 64];

  int nb = N >> 8;
  int x = blockIdx.x & 7;        // XCD id (grid % 8 == 0)
  int u = blockIdx.x >> 3;       // local block within XCD region
  int rcr = nb / RC;             // # of region-columns
  int brow = (x / rcr) * RM + (u % RM);
  int bcol = (x % rcr) * RC + (u / RM);

  int tid = threadIdx.x, w = tid >> 6, lane = tid & 63;
  int wm = w >> 2, wn = w & 3;
  int quad = lane >> 4, l15 = lane & 15;
  int lr = lane >> 3, lc = lane & 7;
  int NT = K >> 6;

  const u16* Ag = A + (long)(brow * 128 + w * 8 + lr) * K + (lc ^ lr) * 8;
  const u16* Bg = Bt + (long)(bcol * 256 + w * 8 + lr) * K + (lc ^ lr) * 8;

  f32x4 acc[4][4] = {};
  bf16x8 a[4][2];  // all 4 m-frags: [mi][kk]
  bf16x8 b[4][2];  // all 4 n-frags: [fi][kk]

#define STAGE_A(c, t)                                                          \
  if ((t) < NT) {                                                              \
    _Pragma("unroll") for (int j = 0; j < 2; j++)                              \
        load16(Ag + (long)(j * 64) * K + (long)(t) * 64,                       \
               &sA[c][(j * 64 + w * 8) * 64]);                                 \
  }
#define STAGE_B(c, t)                                                          \
  if ((t) < NT) {                                                              \
    _Pragma("unroll") for (int j = 0; j < 4; j++)                              \
        load16(Bg + (long)(j * 64) * K + (long)(t) * 64,                       \
               &sB[c][(j * 64 + w * 8) * 64]);                                 \
  }
#define LDAB(c)                                                                \
  _Pragma("unroll") for (int mi = 0; mi < 4; mi++) {                           \
    int r = wm * 64 + mi * 16 + l15;                                           \
    _Pragma("unroll") for (int kk = 0; kk < 2; kk++)                           \
        a[mi][kk] =                                                            \
        *(const bf16x8*)&sA[c][r * 64 + (((kk * 4 + quad) ^ (r & 7)) << 3)];   \
  }                                                                            \
  _Pragma("unroll") for (int fi = 0; fi < 4; fi++) {                           \
    int rn = wn * 64 + fi * 16 + l15;                                          \
    _Pragma("unroll") for (int kk = 0; kk < 2; kk++)                           \
        b[fi][kk] =                                                            \
        *(const bf16x8*)&sB[c][rn * 64 + (((kk * 4 + quad) ^ (rn & 7)) << 3)]; \
  }
#define MFMAH(qm)                                                              \
  _Pragma("unroll") for (int mi = 0; mi < 2; mi++)                             \
  _Pragma("unroll") for (int fi = 0; fi < 4; fi++)                             \
  _Pragma("unroll") for (int kk = 0; kk < 2; kk++)                             \
      acc[(qm)*2 + mi][fi] = __builtin_amdgcn_mfma_f32_16x16x32_bf16(          \
          a[(qm)*2 + mi][kk], b[fi][kk], acc[(qm)*2 + mi][fi], 0, 0, 0);
#define BAR() __builtin_amdgcn_s_barrier()
#define LGKM0()                                      \
  asm volatile("s_waitcnt lgkmcnt(0)" ::: "memory"); \
  __builtin_amdgcn_sched_barrier(0)

#define TILE(c, t)                                                             \
  {                                                                            \
    LDAB(c);                                                                   \
    LGKM0();                                                                   \
    __builtin_amdgcn_s_setprio(1);                                             \
    MFMAH(0);                                                                  \
    __builtin_amdgcn_s_setprio(0);                                             \
    BAR(); /* mid: all waves' reads of buf c complete */                       \
    STAGE_A(c, (t) + 3);                                                       \
    STAGE_B(c, (t) + 3);                                                       \
    __builtin_amdgcn_s_setprio(1);                                             \
    MFMAH(1);                                                                  \
    __builtin_amdgcn_s_setprio(0);                                             \
    if ((t) < NT - 3) {                                                        \
      asm volatile("s_waitcnt vmcnt(12)" ::: "memory");                        \
    } else if ((t) == NT - 3) {                                                \
      asm volatile("s_waitcnt vmcnt(6)" ::: "memory");                         \
    } else {                                                                   \
      asm volatile("s_waitcnt vmcnt(0)" ::: "memory");                         \
    }                                                                          \
    __builtin_amdgcn_sched_barrier(0);                                         \
    BAR(); /* end: t+1's staged data visible to all */                         \
  }

  // prologue: stage tiles 0,1,2 into bufs 0,1,2; drain tile 0, keep 1,2 flying
  STAGE_A(0, 0);
  STAGE_B(0, 0);
  STAGE_A(1, 1);
  STAGE_B(1, 1);
  STAGE_A(2, 2);
  STAGE_B(2, 2);
  asm volatile("s_waitcnt vmcnt(12)" ::: "memory");
  __builtin_amdgcn_sched_barrier(0);
  BAR();

  int kt = 0;
  for (; kt + 2 < NT; kt += 3) {
    TILE(0, kt);
    TILE(1, kt + 1);
    TILE(2, kt + 2);
  }
  // NT = 32: epilogue tiles 30 (buf 0), 31 (buf 1)
  if (kt < NT) { TILE(0, kt); }
  if (kt + 1 < NT) { TILE(1, kt + 1); }

  long orow = (long)brow * 128 + wm * 64;
  int ocol = bcol * 256 + wn * 64;
  if constexpr (!FUSE) {
#pragma unroll
    for (int mi = 0; mi < 4; mi++)
#pragma unroll
      for (int fi = 0; fi < 4; fi++)
#pragma unroll
        for (int r = 0; r < 4; r++)
          cstore(&C[(orow + mi * 16 + quad * 4 + r) * (long)N + ocol + fi * 16 + l15],
                 acc[mi][fi][r]);
  } else {
    // last TILE ended with lgkm0-before-BAR + BAR: all LDS reads drained; safe reuse.
    u16* ep = (u16*)sB + w * (64 * 72);  // per-wave 64x72 u16 transpose tile
    int lane8 = lane >> 3, c8 = (lane & 7) * 8;
    if (bcol >= 16) {
      // ---- V: acc -> bf16 -> ep[d_local][l_local] -> coalesced rows of Vt ----
#pragma unroll
      for (int mi = 0; mi < 4; mi++)
#pragma unroll
        for (int fi = 0; fi < 4; fi++)
#pragma unroll
          for (int r = 0; r < 4; r++)
            ep[(fi * 16 + l15) * 72 + mi * 16 + quad * 4 + r] = f2bf(acc[mi][fi][r]);
      asm volatile("s_waitcnt lgkmcnt(0)" ::: "memory");
      __builtin_amdgcn_sched_barrier(0);
      int h = ((bcol - 16) << 1) | (wn >> 1);
      int bb = (int)(orow >> 11);
      int lbase = (int)(orow & 2047);
      long vbase = ((long)(bb * Hc + h) * HDc + (wn & 1) * 64) * Lc + lbase;
#pragma unroll
      for (int p = 0; p < 8; p++) {
        int dl = p * 8 + lane8;
        uint4 vv = *(const uint4*)&ep[dl * 72 + c8];
        *(uint4*)(Vt + vbase + (long)dl * Lc + c8) = vv;
      }
    } else {
      // ---- Q/K: RMS norm + RoPE fused ----
      bool isQ = (bcol < 8);
      // per-row sum of squares over this wave's 64 cols (all lanes get it)
      float ss[4][4];
#pragma unroll
      for (int mi = 0; mi < 4; mi++)
#pragma unroll
        for (int r = 0; r < 4; r++) {
          float s = 0.f;
#pragma unroll
          for (int fi = 0; fi < 4; fi++) s += acc[mi][fi][r] * acc[mi][fi][r];
#pragma unroll
          for (int m = 1; m < 16; m <<= 1) s += __shfl_xor(s, m);
          ss[mi][r] = s;
        }
      float* red = (float*)sA;  // [128][4] partials
      if (l15 == 0) {
#pragma unroll
        for (int mi = 0; mi < 4; mi++)
#pragma unroll
          for (int r = 0; r < 4; r++)
            red[(wm * 64 + mi * 16 + quad * 4 + r) * 4 + wn] = ss[mi][r];
      }
      __syncthreads();
      float rr[4][4];
#pragma unroll
      for (int mi = 0; mi < 4; mi++)
#pragma unroll
        for (int r = 0; r < 4; r++) {
          float tot = ss[mi][r] + red[(wm * 64 + mi * 16 + quad * 4 + r) * 4 + (wn ^ 1)];
          rr[mi][r] = rsqrtf(tot * (1.f / HDc) + 1e-6f);
        }
      const float* scp = isQ ? qsc : ksc;
      int dh = (wn & 1) * 64;
      float sc[4];
#pragma unroll
      for (int fi = 0; fi < 4; fi++) sc[fi] = scp[dh + fi * 16 + l15];
      constexpr float RS = 0.08838834764831845f;  // 1/sqrt(128)
      float oscale = isQ ? RS : 1.f;
      int dpar = l15 & 1;
      int lg0 = (int)(orow & 2047);
#pragma unroll
      for (int mi = 0; mi < 4; mi++)
#pragma unroll
        for (int fi = 0; fi < 4; fi++) {
          int d = dh + fi * 16 + l15;
          const float* pb = pe + ((d >> 1) << 2) + ((d & 1) << 1);
#pragma unroll
          for (int r = 0; r < 4; r++) {
            int lloc = mi * 16 + quad * 4 + r;
            float v = acc[mi][fi][r] * rr[mi][r] * sc[fi];
            float vp = __shfl_xor(v, 1);
            float2 e = *(const float2*)(pb + (long)(lg0 + lloc) * 256);
            float o = dpar ? (e.x * vp + e.y * v) : (e.x * v + e.y * vp);
            ep[lloc * 72 + fi * 16 + l15] = f2bf(o * oscale);
          }
        }
      asm volatile("s_waitcnt lgkmcnt(0)" ::: "memory");
      __builtin_amdgcn_sched_barrier(0);
      int h = isQ ? ((bcol << 1) | (wn >> 1)) : (((bcol - 8) << 1) | (wn >> 1));
      u16* dst = isQ ? Qr : Kr;
      int bb = (int)(orow >> 11);
      long qbase = ((long)(bb * Hc + h) * Lc + lg0) * HDc + dh;
#pragma unroll
      for (int p = 0; p < 8; p++) {
        int rl = p * 8 + lane8;
        uint4 vv = *(const uint4*)&ep[rl * 72 + c8];
        *(uint4*)(dst + qbase + (long)rl * HDc + c8) = vv;
      }
    }
  }
#undef STAGE_A
#undef STAGE_B
#undef LDAB
#undef MFMAH
#undef BAR
#undef LGKM0
#undef TILE
}

// ------- flash attention v7: async staging (K post-D lds-dma, V reg-staged) -------
__global__ __launch_bounds__(256, 3) void k_attn(const u16* __restrict__ Qr,
                                                 const u16* __restrict__ Kr,
                                                 const u16* __restrict__ Vt,
                                                 u16* __restrict__ Ao) {
  __shared__ u16 smem[24576];  // 48 KB
  u16* sQ = smem;              // [64][128] staging; reused as sP [64][64] (8KB)
  u16* sK = smem + 8192;       // [64][128] 16KB; epilogue: red
  u16* sV = smem + 16384;      // [128][64] 16KB; epilogue: rsum
  u16* sP = sQ;
  int bx = blockIdx.x;
  int bh = (bx & 7) | ((bx >> 8) << 3);
  int lt = (bx >> 3) & 31;
  const u16* Qg = Qr + ((long)bh * Lc + lt * 64) * HDc;
  const u16* Kg = Kr + (long)bh * Lc * HDc;
  const u16* Vg = Vt + (long)bh * HDc * Lc;
  int tid = threadIdx.x, w = tid >> 6, lane = tid & 63;
  int quad = lane >> 4, l15 = lane & 15;
  int wsl = w >> 1, wsm = w & 1;  // S-phase wave grid: l x m
  int wd = w >> 1, wl2 = w & 1;   // PV-phase wave grid: d x l

  // V reg-stage addressing (same pre-swizzled pattern as lds-dma)
  int vrr0 = w * 8 + (lane >> 3);
  int vg0 = (lane & 7) ^ (vrr0 & 7);
  const u16* Vg0 = Vg + (long)(vrr0 + 0)  * Lc + vg0 * 8;
  const u16* Vg1 = Vg + (long)(vrr0 + 32) * Lc + vg0 * 8;
  const u16* Vg2 = Vg + (long)(vrr0 + 64) * Lc + vg0 * 8;
  const u16* Vg3 = Vg + (long)(vrr0 + 96) * Lc + vg0 * 8;
  u16* sVw = sV + (w * 8) * 64 + lane * 8;

  // ---- stage Q once, pull fragments into registers ----
#pragma unroll
  for (int i = 0; i < 4; i++) {
    int r = i * 16 + w * 4 + quad;
    int gch = l15 ^ (r & 15);
    load16(Qg + (long)r * HDc + gch * 8, sQ + (i * 16 + w * 4) * 128);
  }
  __syncthreads();
  bf16x8 qf[2][4];
#pragma unroll
  for (int mi = 0; mi < 2; mi++) {
    int l = wsl * 32 + mi * 16 + l15;
#pragma unroll
    for (int kk = 0; kk < 4; kk++)
      qf[mi][kk] = *(const bf16x8*)&sQ[l * 128 + (((kk * 4 + quad) ^ l15) << 3)];
  }

  // ---- prologue staging for tile 0 ----
#pragma unroll
  for (int i = 0; i < 4; i++) {
    int r = i * 16 + w * 4 + quad;
    int gch = l15 ^ (r & 15);
    load16(Kg + (long)r * HDc + gch * 8, sK + (i * 16 + w * 4) * 128);
  }
  uint4 vr0 = *(const uint4*)(Vg0);
  uint4 vr1 = *(const uint4*)(Vg1);
  uint4 vr2 = *(const uint4*)(Vg2);
  uint4 vr3 = *(const uint4*)(Vg3);

  f32x4 o[4][2] = {};
  float rs[8] = {};
  for (int t = 0; t < 32; t++) {
    int m0 = t * 64;
    __syncthreads();  // A: prev PV done; vmcnt drained -> sK(t) ready, vr = V(t)
    *(uint4*)(sVw + 0 * 32 * 64) = vr0;
    *(uint4*)(sVw + 1 * 32 * 64) = vr1;
    *(uint4*)(sVw + 2 * 32 * 64) = vr2;
    *(uint4*)(sVw + 3 * 32 * 64) = vr3;
    __syncthreads();  // B: sV visible (lgkm-only)
    f32x4 s[2][2] = {};
#pragma unroll
    for (int kk = 0; kk < 4; kk++) {
      bf16x8 bk[2];
#pragma unroll
      for (int ni = 0; ni < 2; ni++) {
        int m = wsm * 32 + ni * 16 + l15;
        bk[ni] = *(const bf16x8*)&sK[m * 128 + (((kk * 4 + quad) ^ l15) << 3)];
      }
#pragma unroll
      for (int mi = 0; mi < 2; mi++)
#pragma unroll
        for (int ni = 0; ni < 2; ni++)
          s[mi][ni] =
              __builtin_amdgcn_mfma_f32_16x16x32_bf16(qf[mi][kk], bk[ni], s[mi][ni], 0, 0, 0);
    }
#pragma unroll
    for (int mi = 0; mi < 2; mi++)
#pragma unroll
      for (int ni = 0; ni < 2; ni++) {
        int pc = wsm * 32 + ni * 16 + l15;
#pragma unroll
        for (int r = 0; r < 4; r++) {
          int pr = wsl * 32 + mi * 16 + quad * 4 + r;
          float p = __expf(s[mi][ni][r]);
          rs[mi * 4 + r] += p;
          unsigned u = __builtin_bit_cast(unsigned, p) + 0x8000u;
          sP[pr * 64 + ((((pc >> 3) ^ (pr & 7)) << 3) | (pc & 7))] = (u16)(u >> 16);
        }
      }
    __syncthreads();  // D: sP visible; all waves done reading sK
    if (t + 1 < 32) {
      int m1 = m0 + 64;
#pragma unroll
      for (int i = 0; i < 4; i++) {
        int r = i * 16 + w * 4 + quad;
        int gch = l15 ^ (r & 15);
        load16(Kg + ((long)(m1 + r)) * HDc + gch * 8, sK + (i * 16 + w * 4) * 128);
      }
      vr0 = *(const uint4*)(Vg0 + m1);
      vr1 = *(const uint4*)(Vg1 + m1);
      vr2 = *(const uint4*)(Vg2 + m1);
      vr3 = *(const uint4*)(Vg3 + m1);
    }
#pragma unroll
    for (int kk = 0; kk < 2; kk++) {
      bf16x8 av[4], bp[2];
#pragma unroll
      for (int mi = 0; mi < 4; mi++) {
        int d = wd * 64 + mi * 16 + l15;
        av[mi] = *(const bf16x8*)&sV[d * 64 + (((kk * 4 + quad) ^ (d & 7)) << 3)];
      }
#pragma unroll
      for (int ni = 0; ni < 2; ni++) {
        int l = wl2 * 32 + ni * 16 + l15;
        bp[ni] = *(const bf16x8*)&sP[l * 64 + (((kk * 4 + quad) ^ (l & 7)) << 3)];
      }
#pragma unroll
      for (int mi = 0; mi < 4; mi++)
#pragma unroll
        for (int ni = 0; ni < 2; ni++)
          o[mi][ni] =
              __builtin_amdgcn_mfma_f32_16x16x32_bf16(av[mi], bp[ni], o[mi][ni], 0, 0, 0);
    }
  }
  __syncthreads();
  float* red  = (float*)sK;  // [64][33]
  float* rsum = (float*)sV;  // [64]
#pragma unroll
  for (int mi = 0; mi < 2; mi++)
#pragma unroll
    for (int r = 0; r < 4; r++) {
      int l = wsl * 32 + mi * 16 + quad * 4 + r;
      red[l * 33 + wsm * 16 + l15] = rs[mi * 4 + r];
    }
  __syncthreads();
  if (tid < 64) {
    float a = 0.f;
#pragma unroll
    for (int j = 0; j < 32; j++) a += red[tid * 33 + j];
    rsum[tid] = a;
  }
  __syncthreads();
  int b = bh >> 4, h = bh & 15;
#pragma unroll
  for (int ni = 0; ni < 2; ni++) {
    int l = wl2 * 32 + ni * 16 + l15;
    float inv = 1.f / rsum[l];
    long rowb = ((long)(b * Lc + lt * 64 + l)) * Dc + h * HDc;
#pragma unroll
    for (int mi = 0; mi < 4; mi++) {
      int d = wd * 64 + mi * 16 + quad * 4;
      ushort4 pk;
      pk.x = f2bf(o[mi][ni][0] * inv);
      pk.y = f2bf(o[mi][ni][1] * inv);
      pk.z = f2bf(o[mi][ni][2] * inv);
      pk.w = f2bf(o[mi][ni][3] * inv);
      *(ushort4*)(Ao + rowb + d) = pk;
    }
  }
}

extern "C" void kernel_launch(void* const* d_in, const int* in_sizes, int n_in,
                              void* d_out, int out_size, void* d_ws, size_t ws_size,
                              hipStream_t stream) {
  const float* x      = (const float*)d_in[0];
  const float* pe     = (const float*)d_in[1];
  const float* w_qkv  = (const float*)d_in[2];
  const float* w_proj = (const float*)d_in[3];
  const float* qs     = (const float*)d_in[4];
  const float* ks     = (const float*)d_in[5];
  float* out = (float*)d_out;
  char* ws = (char*)d_ws;

  u16* xb    = (u16*)(ws);                  //  16.8 MB  x bf16 [4096][2048]
  u16* wqkvT = (u16*)(ws + 16777216);       //  25.2 MB  [6144][2048]
  u16* wpT   = (u16*)(ws + 41943040);       //   8.4 MB  [2048][2048]
  u16* qkvb  = (u16*)(ws + 50331648);       //  (unused)
  u16* Qr    = (u16*)(ws + 100663296);      //  16.8 MB  [B][H][L][HD]
  u16* Kr    = (u16*)(ws + 117440512);      //  16.8 MB
  u16* Vtw   = (u16*)(ws + 134217728);      //  16.8 MB  [B][H][HD][L]
  u16* Ao    = (u16*)(ws + 150994944);      //  16.8 MB  [4096][2048] bf16

  k_prep<<<5120, 256, 0, stream>>>(x, w_qkv, w_proj, xb, wqkvT, wpT);
  // QKV GEMM with fused RMS+RoPE+V-transpose epilogue.
  // grid 768 = 8 XCD regions of 16 brows x 6 bcols
  k_gemm2p<u16, true><<<32 * 24, 512, 0, stream>>>(
      xb, wqkvT, qkvb, Mc, N3c, Dc, 16, 6, pe, qs, ks, Qr, Kr, Vtw);
  k_attn<<<32 * 32, 256, 0, stream>>>(Qr, Kr, Vtw, Ao);
  // proj: grid 256 = 8 XCD regions of 8 brows x 4 bcols
  k_gemm2p<float, false><<<32 * 8, 512, 0, stream>>>(
      Ao, wpT, out, Mc, Dc, Dc, 8, 4, nullptr, nullptr, nullptr, nullptr, nullptr,
      nullptr);
}

// Round 8
// 389.132 us; speedup vs baseline: 1.1317x; 1.0163x over previous
//
#include <hip/hip_runtime.h>

typedef unsigned short u16;
typedef __bf16 bf16x8 __attribute__((ext_vector_type(8)));
typedef float f32x4 __attribute__((ext_vector_type(4)));

#define DEV static __device__ __forceinline__

constexpr int Bc  = 2;
constexpr int Lc  = 2048;
constexpr int Dc  = 2048;
constexpr int Hc  = 16;
constexpr int HDc = 128;
constexpr int Mc  = Bc * Lc;   // 4096
constexpr int N3c = 3 * Dc;    // 6144

DEV u16 f2bf(float f) {
  unsigned u = __builtin_bit_cast(unsigned, f);
  u += 0x7fffu + ((u >> 16) & 1u);
  return (u16)(u >> 16);
}
DEV float bf2f(u16 h) { return __builtin_bit_cast(float, ((unsigned)h) << 16); }

DEV void load16(const void* g, void* l) {
  __builtin_amdgcn_global_load_lds(
      (__attribute__((address_space(1))) void*)(g),
      (__attribute__((address_space(3))) void*)(l), 16, 0, 0);
}

// ---------------- merged prep: x->bf16 convert + both weight transposes ----------------
__global__ __launch_bounds__(256) void k_prep(const float* __restrict__ x,
                                              const float* __restrict__ w_qkv,
                                              const float* __restrict__ w_proj,
                                              u16* __restrict__ xb,
                                              u16* __restrict__ wqkvT,
                                              u16* __restrict__ wpT) {
  __shared__ u16 t[128 * 136];
  int bid = blockIdx.x;
  int tid = threadIdx.x;
  if (bid < 4096) {
    int i = bid * 256 + tid;
    const float4* s = (const float4*)x;
    float4 a = s[2 * i], b = s[2 * i + 1];
    uint4 o;
    o.x = f2bf(a.x) | ((unsigned)f2bf(a.y) << 16);
    o.y = f2bf(a.z) | ((unsigned)f2bf(a.w) << 16);
    o.z = f2bf(b.x) | ((unsigned)f2bf(b.y) << 16);
    o.w = f2bf(b.z) | ((unsigned)f2bf(b.w) << 16);
    ((uint4*)xb)[i] = o;
    return;
  }
  const float* src;
  u16* dst;
  int tiles_c;
  long ss;
  if (bid < 4096 + 768) {
    int bx = bid - 4096;
    src = w_qkv; dst = wqkvT; tiles_c = 48; ss = N3c;
    int tr = bx / tiles_c, tc = bx % tiles_c;
    src += (long)tr * 128 * ss + tc * 128;
    dst += (long)(tc * 128) * Dc + tr * 128;
  } else {
    int bx = bid - 4864;
    src = w_proj; dst = wpT; tiles_c = 16; ss = Dc;
    int tr = bx / tiles_c, tc = bx % tiles_c;
    src += (long)tr * 128 * ss + tc * 128;
    dst += (long)(tc * 128) * Dc + tr * 128;
  }
#pragma unroll
  for (int p = 0; p < 16; p++) {
    int r = p * 8 + (tid >> 5);
    int c4 = (tid & 31) * 4;
    float4 v = *(const float4*)(src + (long)r * ss + c4);
    t[(c4 + 0) * 136 + r] = f2bf(v.x);
    t[(c4 + 1) * 136 + r] = f2bf(v.y);
    t[(c4 + 2) * 136 + r] = f2bf(v.z);
    t[(c4 + 3) * 136 + r] = f2bf(v.w);
  }
  __syncthreads();
#pragma unroll
  for (int p = 0; p < 8; p++) {
    int c = p * 16 + (tid >> 4);
    int r8 = (tid & 15) * 8;
    uint4 v = *(const uint4*)&t[c * 136 + r8];
    *(uint4*)(dst + (long)c * Dc + r8) = v;
  }
}

DEV void cstore(float* p, float v) { *p = v; }
DEV void cstore(u16* p, float v) { *p = f2bf(v); }

// ------- 2-phase 128x256-tile bf16 MFMA GEMM, 3-deep pipeline + 2D XCD regions -------
// K-loop identical to R4 (best measured).  FUSE=true: fused RMS+RoPE (Q/K) and
// V-transpose epilogue (see R7 notes).
template <typename OT, bool FUSE>
__global__ __launch_bounds__(512, 2) void k_gemm2p(const u16* __restrict__ A,
                                                   const u16* __restrict__ Bt,
                                                   OT* __restrict__ C,
                                                   int M, int N, int K,
                                                   int RM, int RC,
                                                   const float* __restrict__ pe,
                                                   const float* __restrict__ qsc,
                                                   const float* __restrict__ ksc,
                                                   u16* __restrict__ Qr,
                                                   u16* __restrict__ Kr,
                                                   u16* __restrict__ Vt) {
  __shared__ __align__(16) u16 sA[3][128 * 64];
  __shared__ __align__(16) u16 sB[3][256 * 64];

  int nb = N >> 8;
  int x = blockIdx.x & 7;        // XCD id (grid % 8 == 0)
  int u = blockIdx.x >> 3;       // local block within XCD region
  int rcr = nb / RC;             // # of region-columns
  int brow = (x / rcr) * RM + (u % RM);
  int bcol = (x % rcr) * RC + (u / RM);

  int tid = threadIdx.x, w = tid >> 6, lane = tid & 63;
  int wm = w >> 2, wn = w & 3;
  int quad = lane >> 4, l15 = lane & 15;
  int lr = lane >> 3, lc = lane & 7;
  int NT = K >> 6;

  const u16* Ag = A + (long)(brow * 128 + w * 8 + lr) * K + (lc ^ lr) * 8;
  const u16* Bg = Bt + (long)(bcol * 256 + w * 8 + lr) * K + (lc ^ lr) * 8;

  f32x4 acc[4][4] = {};
  bf16x8 a[4][2];  // all 4 m-frags: [mi][kk]
  bf16x8 b[4][2];  // all 4 n-frags: [fi][kk]

#define STAGE_A(c, t)                                                          \
  if ((t) < NT) {                                                              \
    _Pragma("unroll") for (int j = 0; j < 2; j++)                              \
        load16(Ag + (long)(j * 64) * K + (long)(t) * 64,                       \
               &sA[c][(j * 64 + w * 8) * 64]);                                 \
  }
#define STAGE_B(c, t)                                                          \
  if ((t) < NT) {                                                              \
    _Pragma("unroll") for (int j = 0; j < 4; j++)                              \
        load16(Bg + (long)(j * 64) * K + (long)(t) * 64,                       \
               &sB[c][(j * 64 + w * 8) * 64]);                                 \
  }
#define LDAB(c)                                                                \
  _Pragma("unroll") for (int mi = 0; mi < 4; mi++) {                           \
    int r = wm * 64 + mi * 16 + l15;                                           \
    _Pragma("unroll") for (int kk = 0; kk < 2; kk++)                           \
        a[mi][kk] =                                                            \
        *(const bf16x8*)&sA[c][r * 64 + (((kk * 4 + quad) ^ (r & 7)) << 3)];   \
  }                                                                            \
  _Pragma("unroll") for (int fi = 0; fi < 4; fi++) {                           \
    int rn = wn * 64 + fi * 16 + l15;                                          \
    _Pragma("unroll") for (int kk = 0; kk < 2; kk++)                           \
        b[fi][kk] =                                                            \
        *(const bf16x8*)&sB[c][rn * 64 + (((kk * 4 + quad) ^ (rn & 7)) << 3)]; \
  }
#define MFMAH(qm)                                                              \
  _Pragma("unroll") for (int mi = 0; mi < 2; mi++)                             \
  _Pragma("unroll") for (int fi = 0; fi < 4; fi++)                             \
  _Pragma("unroll") for (int kk = 0; kk < 2; kk++)                             \
      acc[(qm)*2 + mi][fi] = __builtin_amdgcn_mfma_f32_16x16x32_bf16(          \
          a[(qm)*2 + mi][kk], b[fi][kk], acc[(qm)*2 + mi][fi], 0, 0, 0);
#define BAR() __builtin_amdgcn_s_barrier()
#define LGKM0()                                      \
  asm volatile("s_waitcnt lgkmcnt(0)" ::: "memory"); \
  __builtin_amdgcn_sched_barrier(0)

#define TILE(c, t)                                                             \
  {                                                                            \
    LDAB(c);                                                                   \
    LGKM0();                                                                   \
    __builtin_amdgcn_s_setprio(1);                                             \
    MFMAH(0);                                                                  \
    __builtin_amdgcn_s_setprio(0);                                             \
    BAR(); /* mid: all waves' reads of buf c complete */                       \
    STAGE_A(c, (t) + 3);                                                       \
    STAGE_B(c, (t) + 3);                                                       \
    __builtin_amdgcn_s_setprio(1);                                             \
    MFMAH(1);                                                                  \
    __builtin_amdgcn_s_setprio(0);                                             \
    if ((t) < NT - 3) {                                                        \
      asm volatile("s_waitcnt vmcnt(12)" ::: "memory");                        \
    } else if ((t) == NT - 3) {                                                \
      asm volatile("s_waitcnt vmcnt(6)" ::: "memory");                         \
    } else {                                                                   \
      asm volatile("s_waitcnt vmcnt(0)" ::: "memory");                         \
    }                                                                          \
    __builtin_amdgcn_sched_barrier(0);                                         \
    BAR(); /* end: t+1's staged data visible to all */                         \
  }

  // prologue: stage tiles 0,1,2 into bufs 0,1,2; drain tile 0, keep 1,2 flying
  STAGE_A(0, 0);
  STAGE_B(0, 0);
  STAGE_A(1, 1);
  STAGE_B(1, 1);
  STAGE_A(2, 2);
  STAGE_B(2, 2);
  asm volatile("s_waitcnt vmcnt(12)" ::: "memory");
  __builtin_amdgcn_sched_barrier(0);
  BAR();

  int kt = 0;
  for (; kt + 2 < NT; kt += 3) {
    TILE(0, kt);
    TILE(1, kt + 1);
    TILE(2, kt + 2);
  }
  // NT = 32: epilogue tiles 30 (buf 0), 31 (buf 1)
  if (kt < NT) { TILE(0, kt); }
  if (kt + 1 < NT) { TILE(1, kt + 1); }

  long orow = (long)brow * 128 + wm * 64;
  int ocol = bcol * 256 + wn * 64;
  if constexpr (!FUSE) {
#pragma unroll
    for (int mi = 0; mi < 4; mi++)
#pragma unroll
      for (int fi = 0; fi < 4; fi++)
#pragma unroll
        for (int r = 0; r < 4; r++)
          cstore(&C[(orow + mi * 16 + quad * 4 + r) * (long)N + ocol + fi * 16 + l15],
                 acc[mi][fi][r]);
  } else {
    // last TILE ended with lgkm0-before-BAR + BAR: all LDS reads drained; safe reuse.
    u16* ep = (u16*)sB + w * (64 * 72);  // per-wave 64x72 u16 transpose tile
    int lane8 = lane >> 3, c8 = (lane & 7) * 8;
    if (bcol >= 16) {
      // ---- V: acc -> bf16 -> ep[d_local][l_local] -> coalesced rows of Vt ----
#pragma unroll
      for (int mi = 0; mi < 4; mi++)
#pragma unroll
        for (int fi = 0; fi < 4; fi++)
#pragma unroll
          for (int r = 0; r < 4; r++)
            ep[(fi * 16 + l15) * 72 + mi * 16 + quad * 4 + r] = f2bf(acc[mi][fi][r]);
      asm volatile("s_waitcnt lgkmcnt(0)" ::: "memory");
      __builtin_amdgcn_sched_barrier(0);
      int h = ((bcol - 16) << 1) | (wn >> 1);
      int bb = (int)(orow >> 11);
      int lbase = (int)(orow & 2047);
      long vbase = ((long)(bb * Hc + h) * HDc + (wn & 1) * 64) * Lc + lbase;
#pragma unroll
      for (int p = 0; p < 8; p++) {
        int dl = p * 8 + lane8;
        uint4 vv = *(const uint4*)&ep[dl * 72 + c8];
        *(uint4*)(Vt + vbase + (long)dl * Lc + c8) = vv;
      }
    } else {
      // ---- Q/K: RMS norm + RoPE fused ----
      bool isQ = (bcol < 8);
      float ss[4][4];
#pragma unroll
      for (int mi = 0; mi < 4; mi++)
#pragma unroll
        for (int r = 0; r < 4; r++) {
          float s = 0.f;
#pragma unroll
          for (int fi = 0; fi < 4; fi++) s += acc[mi][fi][r] * acc[mi][fi][r];
#pragma unroll
          for (int m = 1; m < 16; m <<= 1) s += __shfl_xor(s, m);
          ss[mi][r] = s;
        }
      float* red = (float*)sA;  // [128][4] partials
      if (l15 == 0) {
#pragma unroll
        for (int mi = 0; mi < 4; mi++)
#pragma unroll
          for (int r = 0; r < 4; r++)
            red[(wm * 64 + mi * 16 + quad * 4 + r) * 4 + wn] = ss[mi][r];
      }
      __syncthreads();
      float rr[4][4];
#pragma unroll
      for (int mi = 0; mi < 4; mi++)
#pragma unroll
        for (int r = 0; r < 4; r++) {
          float tot = ss[mi][r] + red[(wm * 64 + mi * 16 + quad * 4 + r) * 4 + (wn ^ 1)];
          rr[mi][r] = rsqrtf(tot * (1.f / HDc) + 1e-6f);
        }
      const float* scp = isQ ? qsc : ksc;
      int dh = (wn & 1) * 64;
      float sc[4];
#pragma unroll
      for (int fi = 0; fi < 4; fi++) sc[fi] = scp[dh + fi * 16 + l15];
      constexpr float RS = 0.08838834764831845f;  // 1/sqrt(128)
      float oscale = isQ ? RS : 1.f;
      int dpar = l15 & 1;
      int lg0 = (int)(orow & 2047);
#pragma unroll
      for (int mi = 0; mi < 4; mi++)
#pragma unroll
        for (int fi = 0; fi < 4; fi++) {
          int d = dh + fi * 16 + l15;
          const float* pb = pe + ((d >> 1) << 2) + ((d & 1) << 1);
#pragma unroll
          for (int r = 0; r < 4; r++) {
            int lloc = mi * 16 + quad * 4 + r;
            float v = acc[mi][fi][r] * rr[mi][r] * sc[fi];
            float vp = __shfl_xor(v, 1);
            float2 e = *(const float2*)(pb + (long)(lg0 + lloc) * 256);
            float o = dpar ? (e.x * vp + e.y * v) : (e.x * v + e.y * vp);
            ep[lloc * 72 + fi * 16 + l15] = f2bf(o * oscale);
          }
        }
      asm volatile("s_waitcnt lgkmcnt(0)" ::: "memory");
      __builtin_amdgcn_sched_barrier(0);
      int h = isQ ? ((bcol << 1) | (wn >> 1)) : (((bcol - 8) << 1) | (wn >> 1));
      u16* dst = isQ ? Qr : Kr;
      int bb = (int)(orow >> 11);
      long qbase = ((long)(bb * Hc + h) * Lc + lg0) * HDc + dh;
#pragma unroll
      for (int p = 0; p < 8; p++) {
        int rl = p * 8 + lane8;
        uint4 vv = *(const uint4*)&ep[rl * 72 + c8];
        *(uint4*)(dst + qbase + (long)rl * HDc + c8) = vv;
      }
    }
  }
#undef STAGE_A
#undef STAGE_B
#undef LDAB
#undef MFMAH
#undef BAR
#undef LGKM0
#undef TILE
}

// ------- flash attention v8: QBLK=128, 8 waves, 2 blk/CU, async K/V staging -------
// Grid 512 = 16 lt x 32 bh, fully co-resident (2 blocks/CU, 16 waves/CU).
// LDS 64KB: sQ [128][128] 32K (reused as sP [128][64] 16K), sK [64][128] 16K,
// sV [128][64] 16K.  Per tile: A (syncthreads: prev PV done, K(t)/V(t) landed)
// -> V ds_write -> B -> S=QK^T (4l x 2m wave grid) -> exp -> sP -> D (sK free)
// -> issue K(t+1) lds-dma + V(t+1) reg loads under PV (2d x 4l wave grid).
__global__ __launch_bounds__(512, 4) void k_attn(const u16* __restrict__ Qr,
                                                 const u16* __restrict__ Kr,
                                                 const u16* __restrict__ Vt,
                                                 u16* __restrict__ Ao) {
  __shared__ u16 smem[32768];  // 64 KB
  u16* sQ = smem;              // [128][128] 32KB; reused as sP [128][64] 16KB
  u16* sK = smem + 16384;      // [64][128] 16KB
  u16* sV = smem + 24576;      // [128][64] 16KB
  u16* sP = sQ;
  int bx = blockIdx.x;
  int bh = (bx & 7) | ((bx >> 7) << 3);  // 0..31, bh%8 == XCD id
  int lt = (bx >> 3) & 15;               // 0..15
  const u16* Qg = Qr + ((long)bh * Lc + lt * 128) * HDc;
  const u16* Kg = Kr + (long)bh * Lc * HDc;
  const u16* Vg = Vt + (long)bh * HDc * Lc;
  int tid = threadIdx.x, w = tid >> 6, lane = tid & 63;
  int quad = lane >> 4, l15 = lane & 15;
  int wsl = w >> 1, wsm = w & 1;  // S-phase wave grid: 4l x 2m
  int wd = w >> 2, wl = w & 3;    // PV-phase wave grid: 2d x 4l

  // V reg-stage addressing (pre-swizzled; r&7 invariant across the +64 step)
  int vrr0 = w * 8 + (lane >> 3);           // 0..63
  int vg0 = (lane & 7) ^ (vrr0 & 7);
  const u16* Vg0 = Vg + (long)(vrr0 + 0)  * Lc + vg0 * 8;
  const u16* Vg1 = Vg + (long)(vrr0 + 64) * Lc + vg0 * 8;
  u16* sVw = sV + (w * 8) * 64 + lane * 8;  // rows w*8..w*8+7; +64*64 for hi half

  // ---- stage Q once (coalesced lds-dma), pull fragments into registers ----
#pragma unroll
  for (int i = 0; i < 4; i++) {
    int r = i * 32 + w * 4 + quad;
    int gch = l15 ^ (r & 15);
    load16(Qg + (long)r * HDc + gch * 8, sQ + (i * 32 + w * 4) * 128);
  }
  __syncthreads();
  bf16x8 qf[2][4];
#pragma unroll
  for (int mi = 0; mi < 2; mi++) {
    int l = wsl * 32 + mi * 16 + l15;
#pragma unroll
    for (int kk = 0; kk < 4; kk++)
      qf[mi][kk] = *(const bf16x8*)&sQ[l * 128 + (((kk * 4 + quad) ^ l15) << 3)];
  }

  // ---- prologue staging for tile 0: K via lds-dma, V into regs ----
#pragma unroll
  for (int i = 0; i < 2; i++) {
    int r = i * 32 + w * 4 + quad;
    int gch = l15 ^ (r & 15);
    load16(Kg + (long)r * HDc + gch * 8, sK + (i * 32 + w * 4) * 128);
  }
  uint4 vr0 = *(const uint4*)(Vg0);
  uint4 vr1 = *(const uint4*)(Vg1);

  f32x4 o[4][2] = {};
  float rs[8] = {};
  for (int t = 0; t < 32; t++) {
    int m0 = t * 64;
    __syncthreads();  // A: prev PV done; vmcnt drained -> sK(t) ready, vr = V(t)
    *(uint4*)(sVw + 0 * 64 * 64) = vr0;
    *(uint4*)(sVw + 1 * 64 * 64) = vr1;
    __syncthreads();  // B: sV visible (lgkm-only drain)
    // S = Q K^T  (128 l x 64 m; per wave 32x32)
    f32x4 s[2][2] = {};
#pragma unroll
    for (int kk = 0; kk < 4; kk++) {
      bf16x8 bk[2];
#pragma unroll
      for (int ni = 0; ni < 2; ni++) {
        int m = wsm * 32 + ni * 16 + l15;
        bk[ni] = *(const bf16x8*)&sK[m * 128 + (((kk * 4 + quad) ^ l15) << 3)];
      }
#pragma unroll
      for (int mi = 0; mi < 2; mi++)
#pragma unroll
        for (int ni = 0; ni < 2; ni++)
          s[mi][ni] =
              __builtin_amdgcn_mfma_f32_16x16x32_bf16(qf[mi][kk], bk[ni], s[mi][ni], 0, 0, 0);
    }
    // exp + pack P into sP[l][m] (swizzled), accumulate row sums
#pragma unroll
    for (int mi = 0; mi < 2; mi++)
#pragma unroll
      for (int ni = 0; ni < 2; ni++) {
        int pc = wsm * 32 + ni * 16 + l15;
#pragma unroll
        for (int r = 0; r < 4; r++) {
          int pr = wsl * 32 + mi * 16 + quad * 4 + r;
          float p = __expf(s[mi][ni][r]);
          rs[mi * 4 + r] += p;
          unsigned u = __builtin_bit_cast(unsigned, p) + 0x8000u;
          sP[pr * 64 + ((((pc >> 3) ^ (pr & 7)) << 3) | (pc & 7))] = (u16)(u >> 16);
        }
      }
    __syncthreads();  // D: sP visible; all waves done reading sK
    // issue next tile's staging under PV compute
    if (t + 1 < 32) {
      int m1 = m0 + 64;
#pragma unroll
      for (int i = 0; i < 2; i++) {
        int r = i * 32 + w * 4 + quad;
        int gch = l15 ^ (r & 15);
        load16(Kg + ((long)(m1 + r)) * HDc + gch * 8, sK + (i * 32 + w * 4) * 128);
      }
      vr0 = *(const uint4*)(Vg0 + m1);
      vr1 = *(const uint4*)(Vg1 + m1);
    }
    // O^T += V^T P^T  (128 d x 128 l; per wave 64d x 32l)
#pragma unroll
    for (int kk = 0; kk < 2; kk++) {
      bf16x8 av[4], bp[2];
#pragma unroll
      for (int mi = 0; mi < 4; mi++) {
        int d = wd * 64 + mi * 16 + l15;
        av[mi] = *(const bf16x8*)&sV[d * 64 + (((kk * 4 + quad) ^ (d & 7)) << 3)];
      }
#pragma unroll
      for (int ni = 0; ni < 2; ni++) {
        int l = wl * 32 + ni * 16 + l15;
        bp[ni] = *(const bf16x8*)&sP[l * 64 + (((kk * 4 + quad) ^ (l & 7)) << 3)];
      }
#pragma unroll
      for (int mi = 0; mi < 4; mi++)
#pragma unroll
        for (int ni = 0; ni < 2; ni++)
          o[mi][ni] =
              __builtin_amdgcn_mfma_f32_16x16x32_bf16(av[mi], bp[ni], o[mi][ni], 0, 0, 0);
    }
  }
  // ---- epilogue: reduce row sums, scale, store O ----
  __syncthreads();
  float* red  = (float*)(smem + 16384);  // [128][33] = 16.9KB (spills into dead sV)
  float* rsum = (float*)(smem + 24832);  // [128]
#pragma unroll
  for (int mi = 0; mi < 2; mi++)
#pragma unroll
    for (int r = 0; r < 4; r++) {
      int l = wsl * 32 + mi * 16 + quad * 4 + r;
      red[l * 33 + wsm * 16 + l15] = rs[mi * 4 + r];
    }
  __syncthreads();
  if (tid < 128) {
    float a = 0.f;
#pragma unroll
    for (int j = 0; j < 32; j++) a += red[tid * 33 + j];
    rsum[tid] = a;
  }
  __syncthreads();
  int b = bh >> 4, h = bh & 15;
#pragma unroll
  for (int ni = 0; ni < 2; ni++) {
    int l = wl * 32 + ni * 16 + l15;
    float inv = 1.f / rsum[l];
    long rowb = ((long)(b * Lc + lt * 128 + l)) * Dc + h * HDc;
#pragma unroll
    for (int mi = 0; mi < 4; mi++) {
      int d = wd * 64 + mi * 16 + quad * 4;
      ushort4 pk;
      pk.x = f2bf(o[mi][ni][0] * inv);
      pk.y = f2bf(o[mi][ni][1] * inv);
      pk.z = f2bf(o[mi][ni][2] * inv);
      pk.w = f2bf(o[mi][ni][3] * inv);
      *(ushort4*)(Ao + rowb + d) = pk;
    }
  }
}

extern "C" void kernel_launch(void* const* d_in, const int* in_sizes, int n_in,
                              void* d_out, int out_size, void* d_ws, size_t ws_size,
                              hipStream_t stream) {
  const float* x      = (const float*)d_in[0];
  const float* pe     = (const float*)d_in[1];
  const float* w_qkv  = (const float*)d_in[2];
  const float* w_proj = (const float*)d_in[3];
  const float* qs     = (const float*)d_in[4];
  const float* ks     = (const float*)d_in[5];
  float* out = (float*)d_out;
  char* ws = (char*)d_ws;

  u16* xb    = (u16*)(ws);                  //  16.8 MB  x bf16 [4096][2048]
  u16* wqkvT = (u16*)(ws + 16777216);       //  25.2 MB  [6144][2048]
  u16* wpT   = (u16*)(ws + 41943040);       //   8.4 MB  [2048][2048]
  u16* qkvb  = (u16*)(ws + 50331648);       //  (unused)
  u16* Qr    = (u16*)(ws + 100663296);      //  16.8 MB  [B][H][L][HD]
  u16* Kr    = (u16*)(ws + 117440512);      //  16.8 MB
  u16* Vtw   = (u16*)(ws + 134217728);      //  16.8 MB  [B][H][HD][L]
  u16* Ao    = (u16*)(ws + 150994944);      //  16.8 MB  [4096][2048] bf16

  k_prep<<<5120, 256, 0, stream>>>(x, w_qkv, w_proj, xb, wqkvT, wpT);
  // QKV GEMM with fused RMS+RoPE+V-transpose epilogue.
  k_gemm2p<u16, true><<<32 * 24, 512, 0, stream>>>(
      xb, wqkvT, qkvb, Mc, N3c, Dc, 16, 6, pe, qs, ks, Qr, Kr, Vtw);
  k_attn<<<512, 512, 0, stream>>>(Qr, Kr, Vtw, Ao);
  // proj: grid 256 = 8 XCD regions of 8 brows x 4 bcols
  k_gemm2p<float, false><<<32 * 8, 512, 0, stream>>>(
      Ao, wpT, out, Mc, Dc, Dc, 8, 4, nullptr, nullptr, nullptr, nullptr, nullptr,
      nullptr);
}